// Round 13
// baseline (982.176 us; speedup 1.0000x reference)
//
#include <hip/hip_runtime.h>
#include <hip/hip_bf16.h>

typedef __bf16 bf16x8 __attribute__((ext_vector_type(8)));
typedef float f32x4 __attribute__((ext_vector_type(4)));
typedef unsigned short u16x4 __attribute__((ext_vector_type(4)));
typedef unsigned short u16x8 __attribute__((ext_vector_type(8)));

#define DEVI __device__ __forceinline__

constexpr int N_TOK = 2048;
constexpr int DIM   = 2048;
constexpr int NEXP  = 64;
constexpr int FDIM  = 512;
constexpr int TOPK  = 4;
constexpr int NSH   = 2;
constexpr int HSH   = 2048;

DEVI unsigned short f2b(float f) {
  union { float fv; unsigned u; } v; v.fv = f;
  unsigned r = v.u + 0x7fffu + ((v.u >> 16) & 1u);
  return (unsigned short)(r >> 16);
}
DEVI float b2f(unsigned short h) {
  union { unsigned u; float f; } v; v.u = ((unsigned)h) << 16;
  return v.f;
}
DEVI void gll16(const void* g, void* l) {
  __builtin_amdgcn_global_load_lds((const __attribute__((address_space(1))) unsigned*)g,
                                   (__attribute__((address_space(3))) unsigned*)l, 16, 0, 0);
}
DEVI unsigned cvtpk(float lo, float hi) {
  unsigned r;
  asm("v_cvt_pk_bf16_f32 %0, %1, %2" : "=v"(r) : "v"(lo), "v"(hi));
  return r;
}
// bf16x8 B-fragment from f32 LDS tile, 8 consecutive k rows at one column; row stride str floats.
DEVI bf16x8 fragB(const float* base, int str) {
  union { unsigned u[4]; bf16x8 v; } r;
  #pragma unroll
  for (int p = 0; p < 4; ++p) r.u[p] = cvtpk(base[(2 * p) * str], base[(2 * p + 1) * str]);
  return r.v;
}

// ---------------- x -> bf16 ----------------
__global__ void cvt_x_kernel(const float* __restrict__ x, unsigned short* __restrict__ xb) {
  const size_t i = ((size_t)blockIdx.x * 256 + threadIdx.x) * 8;
  const float4 a = *reinterpret_cast<const float4*>(x + i);
  const float4 b = *reinterpret_cast<const float4*>(x + i + 4);
  u16x8 o;
  o[0] = f2b(a.x); o[1] = f2b(a.y); o[2] = f2b(a.z); o[3] = f2b(a.w);
  o[4] = f2b(b.x); o[5] = f2b(b.y); o[6] = f2b(b.z); o[7] = f2b(b.w);
  *reinterpret_cast<u16x8*>(xb + i) = o;
}

// ---------------- shared weights: transpose + bf16 ----------------
__global__ __launch_bounds__(256)
void tr_shared_kernel(const float* __restrict__ swu, const float* __restrict__ swg,
                      const float* __restrict__ swd, unsigned short* __restrict__ swuT,
                      unsigned short* __restrict__ swgT, unsigned short* __restrict__ swdT) {
  __shared__ float Lf[64][68];
  const int tid = threadIdx.x;
  const int r0 = blockIdx.x * 64, c0 = blockIdx.y * 64;
  const int z = blockIdx.z, mat = z >> 1;
  const size_t soff = (size_t)(z & 1) * DIM * HSH;
  const float* in = (mat == 0 ? swu : mat == 1 ? swg : swd) + soff;
  unsigned short* ot = (mat == 0 ? swuT : mat == 1 ? swgT : swdT) + soff;
  #pragma unroll
  for (int j = 0; j < 4; ++j) {
    const int idx = j * 1024 + tid * 4;
    const int row = idx >> 6, col = idx & 63;
    const float4 v = *reinterpret_cast<const float4*>(in + (size_t)(r0 + row) * 2048 + c0 + col);
    *reinterpret_cast<float4*>(&Lf[row][col]) = v;
  }
  __syncthreads();
  #pragma unroll
  for (int j = 0; j < 4; ++j) {
    const int idx = j * 1024 + tid * 4;
    const int orow = idx >> 6, ocol = idx & 63;
    u16x4 o;
    o[0] = f2b(Lf[ocol][orow]);     o[1] = f2b(Lf[ocol + 1][orow]);
    o[2] = f2b(Lf[ocol + 2][orow]); o[3] = f2b(Lf[ocol + 3][orow]);
    *reinterpret_cast<u16x4*>(ot + (size_t)(c0 + orow) * 2048 + r0 + ocol) = o;
  }
}

// ---------------- Router ----------------
__global__ __launch_bounds__(256)
void router_kernel(const float* __restrict__ x, const float* __restrict__ rw,
                   const float* __restrict__ rb, int* __restrict__ cnt,
                   int* __restrict__ listTok, float* __restrict__ listW,
                   int* __restrict__ tokEP) {
  __shared__ float Lx[8][128];
  const int tid = threadIdx.x;
  const int lane = tid & 63;
  const int wave = tid >> 6;
  const int tokBase = blockIdx.x * 8;

  float acc0 = 0.f, acc1 = 0.f;
  for (int dc = 0; dc < DIM; dc += 128) {
    __syncthreads();
    {
      const int idx = tid * 4;
      const int row = idx >> 7, col = idx & 127;
      *reinterpret_cast<float4*>(&Lx[row][col]) =
          *reinterpret_cast<const float4*>(x + (size_t)(tokBase + row) * DIM + dc + col);
    }
    __syncthreads();
    #pragma unroll 16
    for (int dd = 0; dd < 128; ++dd) {
      const float r = rw[(size_t)(dc + dd) * NEXP + lane];
      acc0 = fmaf(Lx[wave * 2 + 0][dd], r, acc0);
      acc1 = fmaf(Lx[wave * 2 + 1][dd], r, acc1);
    }
  }

  const float bias = rb[lane];
  #pragma unroll
  for (int t = 0; t < 2; ++t) {
    const float v = (t == 0) ? acc0 : acc1;
    const int token = tokBase + wave * 2 + t;
    float m = v;
    #pragma unroll
    for (int o = 32; o > 0; o >>= 1) m = fmaxf(m, __shfl_xor(m, o));
    const float p = expf(v - m);
    float ss = p;
    #pragma unroll
    for (int o = 32; o > 0; o >>= 1) ss += __shfl_xor(ss, o);
    const float score = p / ss;
    float cur = v + bias;
    float wk[TOPK]; int ik[TOPK]; float wsum = 0.f;
    #pragma unroll
    for (int k = 0; k < TOPK; ++k) {
      float tm = cur;
      #pragma unroll
      for (int o = 32; o > 0; o >>= 1) tm = fmaxf(tm, __shfl_xor(tm, o));
      const unsigned long long msk = __ballot(cur == tm);
      const int sel = (int)__builtin_ctzll(msk);
      const float w = __shfl(score, sel);
      wk[k] = w; ik[k] = sel; wsum += w;
      if (lane == sel) cur = -3.4e38f;
    }
    if (lane < TOPK) {
      const int e = ik[lane];
      const float w = wk[lane] / wsum;
      const int slot = atomicAdd(&cnt[e], 1);
      listTok[(size_t)e * N_TOK + slot] = token;
      listW[(size_t)e * N_TOK + slot] = w;
      tokEP[token * TOPK + lane] = (e << 16) | slot;
    }
  }
}

__global__ void scan_kernel(const int* __restrict__ cnt, int* __restrict__ off) {
  if (threadIdx.x == 0) {
    int s = 0;
    for (int e = 0; e < NEXP; ++e) { off[e] = s; s += cnt[e]; }
  }
}

// ---------------- Shared up (fused U+G): BM=128, BN=64(x2 mats), BK=64, bf16, single-buf ----------------
__global__ __launch_bounds__(256, 4)
void up_shared(const unsigned short* __restrict__ xb,
               const unsigned short* __restrict__ WuT, const unsigned short* __restrict__ WgT,
               unsigned short* __restrict__ H) {
  constexpr int NT = DIM / 64;  // 32
  const int tid = threadIdx.x;
  const int f0 = blockIdx.x * 64;
  const int s  = blockIdx.y;
  const int m0 = blockIdx.z * 128;

  __shared__ __align__(16) unsigned short Al[8][128][8];   // 16 KB
  __shared__ __align__(16) unsigned short BuL[8][64][8];   //  8 KB
  __shared__ __align__(16) unsigned short BgL[8][64][8];   //  8 KB

  const int wid = tid >> 6, l = tid & 63;
  const int lc = l & 15, hi = l >> 4;

  const unsigned short* pa0 = xb + (size_t)(m0 + l) * DIM;
  const unsigned short* pa1 = xb + (size_t)(m0 + 64 + l) * DIM;
  const unsigned short* pbu = WuT + (size_t)s * HSH * DIM + (size_t)(f0 + l) * DIM;
  const unsigned short* pbg = WgT + (size_t)s * HSH * DIM + (size_t)(f0 + l) * DIM;

  f32x4 aU[2][4], aG[2][4];
  #pragma unroll
  for (int i = 0; i < 2; ++i)
    #pragma unroll
    for (int j = 0; j < 4; ++j) { aU[i][j] = f32x4{0,0,0,0}; aG[i][j] = f32x4{0,0,0,0}; }

  for (int g = 0; g < NT; ++g) {
    const int d0 = g * 64;
    #pragma unroll
    for (int i = 0; i < 4; ++i) {           // A: 16 wave-loads total
      const int idx = wid * 4 + i;
      const int p = idx >> 1, hf = idx & 1;
      gll16((hf ? pa1 : pa0) + d0 + p * 8, &Al[p][hf * 64][0]);
    }
    #pragma unroll
    for (int i = 0; i < 2; ++i) {           // B: 8+8 wave-loads total
      const int p = wid * 2 + i;
      gll16(pbu + d0 + p * 8, &BuL[p][0][0]);
      gll16(pbg + d0 + p * 8, &BgL[p][0][0]);
    }
    __syncthreads();
    #pragma unroll
    for (int ks = 0; ks < 2; ++ks) {
      bf16x8 af[2], bu[4], bg[4];
      #pragma unroll
      for (int mi = 0; mi < 2; ++mi)
        af[mi] = *reinterpret_cast<const bf16x8*>(&Al[ks * 4 + hi][wid * 32 + mi * 16 + lc][0]);
      #pragma unroll
      for (int ni = 0; ni < 4; ++ni) {
        bu[ni] = *reinterpret_cast<const bf16x8*>(&BuL[ks * 4 + hi][ni * 16 + lc][0]);
        bg[ni] = *reinterpret_cast<const bf16x8*>(&BgL[ks * 4 + hi][ni * 16 + lc][0]);
      }
      #pragma unroll
      for (int mi = 0; mi < 2; ++mi)
        #pragma unroll
        for (int ni = 0; ni < 4; ++ni) {
          aU[mi][ni] = __builtin_amdgcn_mfma_f32_16x16x32_bf16(af[mi], bu[ni], aU[mi][ni], 0, 0, 0);
          aG[mi][ni] = __builtin_amdgcn_mfma_f32_16x16x32_bf16(af[mi], bg[ni], aG[mi][ni], 0, 0, 0);
        }
    }
    __syncthreads();
  }

  #pragma unroll
  for (int mi = 0; mi < 2; ++mi)
    #pragma unroll
    for (int ni = 0; ni < 4; ++ni)
      #pragma unroll
      for (int r2 = 0; r2 < 4; ++r2) {
        const int row = wid * 32 + mi * 16 + hi * 4 + r2;
        const int col = f0 + ni * 16 + lc;
        const float g = aG[mi][ni][r2], u = aU[mi][ni][r2];
        H[((size_t)s * N_TOK + m0 + row) * HSH + col] = f2b((g / (1.f + __expf(-g))) * u);
      }
}

// ---------------- Shared down: BM=128, BN=128, K-split x4 -> bf16 partials ----------------
__global__ __launch_bounds__(256, 4)
void down_shared(const unsigned short* __restrict__ Hs, const unsigned short* __restrict__ swdT,
                 unsigned short* __restrict__ shP) {
  constexpr int NT = 16;  // K-chunk 1024
  const int tid = threadIdx.x;
  const int x0 = blockIdx.x * 128;
  const int kc = blockIdx.y;            // 0..3
  const int m0 = blockIdx.z * 128;
  const int seg = kc >> 1;
  const int kb = (kc & 1) * 1024;

  __shared__ __align__(16) unsigned short Al[8][128][8];   // 16 KB
  __shared__ __align__(16) unsigned short Bl[8][128][8];   // 16 KB

  const int wid = tid >> 6, l = tid & 63;
  const int lc = l & 15, hi = l >> 4;

  const unsigned short* pa0 = Hs + ((size_t)seg * N_TOK + m0 + l) * HSH + kb;
  const unsigned short* pa1 = Hs + ((size_t)seg * N_TOK + m0 + 64 + l) * HSH + kb;
  const unsigned short* pb0 = swdT + (size_t)seg * HSH * DIM + (size_t)(x0 + l) * HSH + kb;
  const unsigned short* pb1 = swdT + (size_t)seg * HSH * DIM + (size_t)(x0 + 64 + l) * HSH + kb;

  f32x4 acc[2][8];
  #pragma unroll
  for (int i = 0; i < 2; ++i)
    #pragma unroll
    for (int j = 0; j < 8; ++j) acc[i][j] = f32x4{0,0,0,0};

  for (int g = 0; g < NT; ++g) {
    const int d0 = g * 64;
    #pragma unroll
    for (int i = 0; i < 4; ++i) {
      const int idx = wid * 4 + i;
      const int p = idx >> 1, hf = idx & 1;
      gll16((hf ? pa1 : pa0) + d0 + p * 8, &Al[p][hf * 64][0]);
      gll16((hf ? pb1 : pb0) + d0 + p * 8, &Bl[p][hf * 64][0]);
    }
    __syncthreads();
    #pragma unroll
    for (int ks = 0; ks < 2; ++ks) {
      bf16x8 af[2], bq[8];
      #pragma unroll
      for (int mi = 0; mi < 2; ++mi)
        af[mi] = *reinterpret_cast<const bf16x8*>(&Al[ks * 4 + hi][wid * 32 + mi * 16 + lc][0]);
      #pragma unroll
      for (int ni = 0; ni < 8; ++ni)
        bq[ni] = *reinterpret_cast<const bf16x8*>(&Bl[ks * 4 + hi][ni * 16 + lc][0]);
      #pragma unroll
      for (int mi = 0; mi < 2; ++mi)
        #pragma unroll
        for (int ni = 0; ni < 8; ++ni)
          acc[mi][ni] = __builtin_amdgcn_mfma_f32_16x16x32_bf16(af[mi], bq[ni], acc[mi][ni], 0, 0, 0);
    }
    __syncthreads();
  }

  unsigned short* pout = shP + (size_t)kc * N_TOK * DIM;
  #pragma unroll
  for (int mi = 0; mi < 2; ++mi)
    #pragma unroll
    for (int ni = 0; ni < 8; ++ni)
      #pragma unroll
      for (int r2 = 0; r2 < 4; ++r2) {
        const int row = wid * 32 + mi * 16 + hi * 4 + r2;
        const int col = x0 + ni * 16 + lc;
        pout[(size_t)(m0 + row) * DIM + col] = f2b(acc[mi][ni][r2]);
      }
}

// ---------------- Routed up (fused U+G): BM=256, BN=64(x2), BK=32, f32 B via gll16+fragB ----------------
__global__ __launch_bounds__(256, 3)
void up_routed(const unsigned short* __restrict__ xb,
               const float* __restrict__ Wu, const float* __restrict__ Wg,
               const int* __restrict__ cnt, const int* __restrict__ off,
               const int* __restrict__ listTok, const float* __restrict__ listW,
               unsigned short* __restrict__ H) {
  constexpr int NT = DIM / 32;  // 64
  const int tid = threadIdx.x;
  const int f0 = blockIdx.x * 64;
  const int e  = blockIdx.y;
  const int m0 = blockIdx.z * 256;
  const int c = cnt[e];
  if (m0 >= c) return;
  const int rc = min(256, c - m0);
  const int rowbase = off[e] + m0;

  __shared__ __align__(16) unsigned short Al[4][256][8];   // 16 KB
  __shared__ __align__(16) float Bfu[32][64];              //  8 KB
  __shared__ __align__(16) float Bfg[32][64];              //  8 KB
  __shared__ float wSs[256];

  wSs[tid] = (m0 + tid < c) ? listW[(size_t)e * N_TOK + m0 + tid] : 0.f;

  const int wid = tid >> 6, l = tid & 63;
  const int lc = l & 15, hi = l >> 4;

  const unsigned short* pa[4];
  #pragma unroll
  for (int j = 0; j < 4; ++j) {
    const int tok = listTok[(size_t)e * N_TOK + min(m0 + j * 64 + l, c - 1)];
    pa[j] = xb + (size_t)tok * DIM;
  }
  const float* pwu = Wu + (size_t)e * DIM * FDIM + (size_t)(l >> 4) * FDIM + f0 + (l & 15) * 4;
  const float* pwg = Wg + (size_t)e * DIM * FDIM + (size_t)(l >> 4) * FDIM + f0 + (l & 15) * 4;

  f32x4 aU[4][4], aG[4][4];
  #pragma unroll
  for (int i = 0; i < 4; ++i)
    #pragma unroll
    for (int j = 0; j < 4; ++j) { aU[i][j] = f32x4{0,0,0,0}; aG[i][j] = f32x4{0,0,0,0}; }

  for (int g = 0; g < NT; ++g) {
    const int d0 = g * 32;
    #pragma unroll
    for (int i = 0; i < 4; ++i) {           // A: 16 wave-loads total (4 planes x 4 row-groups)
      const int idx = wid * 4 + i;
      const int p = idx >> 2, j = idx & 3;
      gll16(pa[j] + d0 + p * 8, &Al[p][j * 64][0]);
    }
    #pragma unroll
    for (int i = 0; i < 2; ++i) {           // B: 8+8 wave-loads (4 k-rows each)
      const int krow = (wid * 2 + i) * 4;
      gll16(pwu + (size_t)(d0 + krow) * FDIM, &Bfu[krow][0]);
      gll16(pwg + (size_t)(d0 + krow) * FDIM, &Bfg[krow][0]);
    }
    __syncthreads();
    {
      bf16x8 af[4];
      #pragma unroll
      for (int mi = 0; mi < 4; ++mi)
        af[mi] = *reinterpret_cast<const bf16x8*>(&Al[hi][wid * 64 + mi * 16 + lc][0]);
      #pragma unroll
      for (int ni = 0; ni < 4; ++ni) {
        const bf16x8 bu = fragB(&Bfu[hi * 8][ni * 16 + lc], 64);
        const bf16x8 bg = fragB(&Bfg[hi * 8][ni * 16 + lc], 64);
        #pragma unroll
        for (int mi = 0; mi < 4; ++mi) {
          aU[mi][ni] = __builtin_amdgcn_mfma_f32_16x16x32_bf16(af[mi], bu, aU[mi][ni], 0, 0, 0);
          aG[mi][ni] = __builtin_amdgcn_mfma_f32_16x16x32_bf16(af[mi], bg, aG[mi][ni], 0, 0, 0);
        }
      }
    }
    __syncthreads();
  }

  #pragma unroll
  for (int mi = 0; mi < 4; ++mi)
    #pragma unroll
    for (int ni = 0; ni < 4; ++ni)
      #pragma unroll
      for (int r2 = 0; r2 < 4; ++r2) {
        const int row = wid * 64 + mi * 16 + hi * 4 + r2;
        if (row < rc) {
          const int col = f0 + ni * 16 + lc;
          const float g = aG[mi][ni][r2], u = aU[mi][ni][r2];
          const float h = (g / (1.f + __expf(-g))) * u * wSs[row];
          H[(size_t)(rowbase + row) * FDIM + col] = f2b(h);
        }
      }
}

// ---------------- Routed down: BM=256, BN=64, BK=32, f32 B via gll16+fragB -> P ----------------
__global__ __launch_bounds__(256, 3)
void down_routed(const unsigned short* __restrict__ Hr, const float* __restrict__ wd,
                 const int* __restrict__ cnt, const int* __restrict__ off,
                 unsigned short* __restrict__ P) {
  constexpr int NT = FDIM / 32;  // 16
  const int tid = threadIdx.x;
  const int x0 = blockIdx.x * 64;
  const int e  = blockIdx.y;
  const int m0 = blockIdx.z * 256;
  const int c = cnt[e];
  if (m0 >= c) return;
  const int rc = min(256, c - m0);
  const int rowbase = off[e] + m0;

  __shared__ __align__(16) unsigned short Al[4][256][8];   // 16 KB
  __shared__ __align__(16) float Bf[32][64];               //  8 KB

  const int wid = tid >> 6, l = tid & 63;
  const int lc = l & 15, hi = l >> 4;

  const unsigned short* pa[4];
  #pragma unroll
  for (int j = 0; j < 4; ++j)
    pa[j] = Hr + (size_t)(rowbase + min(j * 64 + l, c - m0 - 1)) * FDIM;

  const float* pwd = wd + (size_t)e * FDIM * DIM + (size_t)(l >> 4) * DIM + x0 + (l & 15) * 4;

  f32x4 acc[4][4];
  #pragma unroll
  for (int i = 0; i < 4; ++i)
    #pragma unroll
    for (int j = 0; j < 4; ++j) acc[i][j] = f32x4{0,0,0,0};

  for (int g = 0; g < NT; ++g) {
    const int d0 = g * 32;
    #pragma unroll
    for (int i = 0; i < 4; ++i) {           // A: 16 wave-loads
      const int idx = wid * 4 + i;
      const int p = idx >> 2, j = idx & 3;
      gll16(pa[j] + d0 + p * 8, &Al[p][j * 64][0]);
    }
    #pragma unroll
    for (int i = 0; i < 2; ++i) {           // B: 8 wave-loads (4 k-rows each)
      const int krow = (wid * 2 + i) * 4;
      gll16(pwd + (size_t)(d0 + krow) * DIM, &Bf[krow][0]);
    }
    __syncthreads();
    {
      bf16x8 af[4];
      #pragma unroll
      for (int mi = 0; mi < 4; ++mi)
        af[mi] = *reinterpret_cast<const bf16x8*>(&Al[hi][wid * 64 + mi * 16 + lc][0]);
      #pragma unroll
      for (int ni = 0; ni < 4; ++ni) {
        const bf16x8 bq = fragB(&Bf[hi * 8][ni * 16 + lc], 64);
        #pragma unroll
        for (int mi = 0; mi < 4; ++mi)
          acc[mi][ni] = __builtin_amdgcn_mfma_f32_16x16x32_bf16(af[mi], bq, acc[mi][ni], 0, 0, 0);
      }
    }
    __syncthreads();
  }

  #pragma unroll
  for (int mi = 0; mi < 4; ++mi)
    #pragma unroll
    for (int ni = 0; ni < 4; ++ni)
      #pragma unroll
      for (int r2 = 0; r2 < 4; ++r2) {
        const int row = wid * 64 + mi * 16 + hi * 4 + r2;
        if (row < rc) {
          const int col = x0 + ni * 16 + lc;
          P[(size_t)(rowbase + row) * DIM + col] = f2b(acc[mi][ni][r2]);
        }
      }
}

// ---------------- Combine: out[n] = sum_k routedP[slot(n,k)] + sum_j shP[j][n] ----------------
__global__ __launch_bounds__(256)
void combine_kernel(const int* __restrict__ tokEP, const int* __restrict__ off,
                    const unsigned short* __restrict__ P, const unsigned short* __restrict__ shP,
                    float* __restrict__ out) {
  const int n = blockIdx.x;
  const int tid = threadIdx.x;
  int rows[4];
  #pragma unroll
  for (int k = 0; k < TOPK; ++k) {
    const int ep = tokEP[n * TOPK + k];
    rows[k] = off[ep >> 16] + (ep & 0xffff);
  }
  const int cc = tid * 8;
  float4 o0 = {0, 0, 0, 0}, o1 = {0, 0, 0, 0};
  #pragma unroll
  for (int k = 0; k < TOPK; ++k) {
    const u16x8 v = *reinterpret_cast<const u16x8*>(P + (size_t)rows[k] * DIM + cc);
    o0.x += b2f(v[0]); o0.y += b2f(v[1]); o0.z += b2f(v[2]); o0.w += b2f(v[3]);
    o1.x += b2f(v[4]); o1.y += b2f(v[5]); o1.z += b2f(v[6]); o1.w += b2f(v[7]);
  }
  #pragma unroll
  for (int j = 0; j < 4; ++j) {
    const u16x8 v = *reinterpret_cast<const u16x8*>(shP + ((size_t)j * N_TOK + n) * DIM + cc);
    o0.x += b2f(v[0]); o0.y += b2f(v[1]); o0.z += b2f(v[2]); o0.w += b2f(v[3]);
    o1.x += b2f(v[4]); o1.y += b2f(v[5]); o1.z += b2f(v[6]); o1.w += b2f(v[7]);
  }
  float* po = out + (size_t)n * DIM + cc;
  *reinterpret_cast<float4*>(po) = o0;
  *reinterpret_cast<float4*>(po + 4) = o1;
}

extern "C" void kernel_launch(void* const* d_in, const int* in_sizes, int n_in,
                              void* d_out, int out_size, void* d_ws, size_t ws_size,
                              hipStream_t stream) {
  const float* x   = (const float*)d_in[0];
  const float* rw  = (const float*)d_in[1];
  const float* rb  = (const float*)d_in[2];
  const float* wg  = (const float*)d_in[3];
  const float* wu  = (const float*)d_in[4];
  const float* wd  = (const float*)d_in[5];
  const float* swg = (const float*)d_in[6];
  const float* swu = (const float*)d_in[7];
  const float* swd = (const float*)d_in[8];
  float* out = (float*)d_out;
  char* ws = (char*)d_ws;

  int* cnt = (int*)ws;
  int* off = (int*)(ws + 256);
  int* tokEP = (int*)(ws + 4096);
  int* listTok = (int*)(ws + 64 * 1024);
  float* listW = (float*)(ws + 576 * 1024);
  unsigned short* xb   = (unsigned short*)(ws + (size_t) 2 * 1024 * 1024);  //  8 MB
  unsigned short* Hr   = (unsigned short*)(ws + (size_t)10 * 1024 * 1024);  //  8 MB
  unsigned short* Hs   = (unsigned short*)(ws + (size_t)18 * 1024 * 1024);  // 16 MB
  unsigned short* swuT = (unsigned short*)(ws + (size_t)34 * 1024 * 1024);  // 16 MB
  unsigned short* swgT = (unsigned short*)(ws + (size_t)50 * 1024 * 1024);  // 16 MB
  unsigned short* swdT = (unsigned short*)(ws + (size_t)66 * 1024 * 1024);  // 16 MB
  unsigned short* P    = (unsigned short*)(ws + (size_t)82 * 1024 * 1024);  // 32 MB
  // shP aliases swuT+swgT (32 MB) — dead after up_shared completes (stream-serial).
  unsigned short* shP  = swuT;

  hipMemsetAsync(cnt, 0, NEXP * sizeof(int), stream);
  cvt_x_kernel<<<(N_TOK * DIM) / (256 * 8), 256, 0, stream>>>(x, xb);
  router_kernel<<<N_TOK / 8, 256, 0, stream>>>(x, rw, rb, cnt, listTok, listW, tokEP);
  scan_kernel<<<1, 64, 0, stream>>>(cnt, off);
  tr_shared_kernel<<<dim3(32, 32, 6), 256, 0, stream>>>(swu, swg, swd, swuT, swgT, swdT);

  up_shared<<<dim3(HSH / 64, NSH, N_TOK / 128), 256, 0, stream>>>(xb, swuT, swgT, Hs);
  up_routed<<<dim3(FDIM / 64, NEXP, 8), 256, 0, stream>>>(xb, wu, wg, cnt, off, listTok, listW, Hr);
  down_shared<<<dim3(DIM / 128, 4, N_TOK / 128), 256, 0, stream>>>(Hs, swdT, shP);
  down_routed<<<dim3(DIM / 64, NEXP, 8), 256, 0, stream>>>(Hr, wd, cnt, off, P);
  combine_kernel<<<N_TOK, 256, 0, stream>>>(tokEP, off, P, shP, out);
}

// Round 14
// 643.329 us; speedup vs baseline: 1.5267x; 1.5267x over previous
//
#include <hip/hip_runtime.h>
#include <hip/hip_bf16.h>

typedef __bf16 bf16x8 __attribute__((ext_vector_type(8)));
typedef float f32x4 __attribute__((ext_vector_type(4)));
typedef unsigned short u16x4 __attribute__((ext_vector_type(4)));
typedef unsigned short u16x8 __attribute__((ext_vector_type(8)));

#define DEVI __device__ __forceinline__

constexpr int N_TOK = 2048;
constexpr int DIM   = 2048;
constexpr int NEXP  = 64;
constexpr int FDIM  = 512;
constexpr int TOPK  = 4;
constexpr int NSH   = 2;
constexpr int HSH   = 2048;

DEVI unsigned short f2b(float f) {
  union { float fv; unsigned u; } v; v.fv = f;
  unsigned r = v.u + 0x7fffu + ((v.u >> 16) & 1u);
  return (unsigned short)(r >> 16);
}
DEVI float b2f(unsigned short h) {
  union { unsigned u; float f; } v; v.u = ((unsigned)h) << 16;
  return v.f;
}
DEVI void gll16(const void* g, void* l) {
  __builtin_amdgcn_global_load_lds((const __attribute__((address_space(1))) unsigned*)g,
                                   (__attribute__((address_space(3))) unsigned*)l, 16, 0, 0);
}
DEVI unsigned cvtpk(float lo, float hi) {
  unsigned r;
  asm("v_cvt_pk_bf16_f32 %0, %1, %2" : "=v"(r) : "v"(lo), "v"(hi));
  return r;
}
// bf16x8 B-fragment from f32 LDS tile, 8 consecutive k rows at one column; row stride str floats.
DEVI bf16x8 fragB(const float* base, int str) {
  union { unsigned u[4]; bf16x8 v; } r;
  #pragma unroll
  for (int p = 0; p < 4; ++p) r.u[p] = cvtpk(base[(2 * p) * str], base[(2 * p + 1) * str]);
  return r.v;
}

// ---------------- x -> bf16 ----------------
__global__ void cvt_x_kernel(const float* __restrict__ x, unsigned short* __restrict__ xb) {
  const size_t i = ((size_t)blockIdx.x * 256 + threadIdx.x) * 8;
  const float4 a = *reinterpret_cast<const float4*>(x + i);
  const float4 b = *reinterpret_cast<const float4*>(x + i + 4);
  u16x8 o;
  o[0] = f2b(a.x); o[1] = f2b(a.y); o[2] = f2b(a.z); o[3] = f2b(a.w);
  o[4] = f2b(b.x); o[5] = f2b(b.y); o[6] = f2b(b.z); o[7] = f2b(b.w);
  *reinterpret_cast<u16x8*>(xb + i) = o;
}

// ---------------- shared weights: transpose + bf16 ----------------
__global__ __launch_bounds__(256)
void tr_shared_kernel(const float* __restrict__ swu, const float* __restrict__ swg,
                      const float* __restrict__ swd, unsigned short* __restrict__ swuT,
                      unsigned short* __restrict__ swgT, unsigned short* __restrict__ swdT) {
  __shared__ float Lf[64][68];
  const int tid = threadIdx.x;
  const int r0 = blockIdx.x * 64, c0 = blockIdx.y * 64;
  const int z = blockIdx.z, mat = z >> 1;
  const size_t soff = (size_t)(z & 1) * DIM * HSH;
  const float* in = (mat == 0 ? swu : mat == 1 ? swg : swd) + soff;
  unsigned short* ot = (mat == 0 ? swuT : mat == 1 ? swgT : swdT) + soff;
  #pragma unroll
  for (int j = 0; j < 4; ++j) {
    const int idx = j * 1024 + tid * 4;
    const int row = idx >> 6, col = idx & 63;
    const float4 v = *reinterpret_cast<const float4*>(in + (size_t)(r0 + row) * 2048 + c0 + col);
    *reinterpret_cast<float4*>(&Lf[row][col]) = v;
  }
  __syncthreads();
  #pragma unroll
  for (int j = 0; j < 4; ++j) {
    const int idx = j * 1024 + tid * 4;
    const int orow = idx >> 6, ocol = idx & 63;
    u16x4 o;
    o[0] = f2b(Lf[ocol][orow]);     o[1] = f2b(Lf[ocol + 1][orow]);
    o[2] = f2b(Lf[ocol + 2][orow]); o[3] = f2b(Lf[ocol + 3][orow]);
    *reinterpret_cast<u16x4*>(ot + (size_t)(c0 + orow) * 2048 + r0 + ocol) = o;
  }
}

// ---------------- Router ----------------
__global__ __launch_bounds__(256)
void router_kernel(const float* __restrict__ x, const float* __restrict__ rw,
                   const float* __restrict__ rb, int* __restrict__ cnt,
                   int* __restrict__ listTok, float* __restrict__ listW,
                   int* __restrict__ tokEP) {
  __shared__ float Lx[8][128];
  const int tid = threadIdx.x;
  const int lane = tid & 63;
  const int wave = tid >> 6;
  const int tokBase = blockIdx.x * 8;

  float acc0 = 0.f, acc1 = 0.f;
  for (int dc = 0; dc < DIM; dc += 128) {
    __syncthreads();
    {
      const int idx = tid * 4;
      const int row = idx >> 7, col = idx & 127;
      *reinterpret_cast<float4*>(&Lx[row][col]) =
          *reinterpret_cast<const float4*>(x + (size_t)(tokBase + row) * DIM + dc + col);
    }
    __syncthreads();
    #pragma unroll 16
    for (int dd = 0; dd < 128; ++dd) {
      const float r = rw[(size_t)(dc + dd) * NEXP + lane];
      acc0 = fmaf(Lx[wave * 2 + 0][dd], r, acc0);
      acc1 = fmaf(Lx[wave * 2 + 1][dd], r, acc1);
    }
  }

  const float bias = rb[lane];
  #pragma unroll
  for (int t = 0; t < 2; ++t) {
    const float v = (t == 0) ? acc0 : acc1;
    const int token = tokBase + wave * 2 + t;
    float m = v;
    #pragma unroll
    for (int o = 32; o > 0; o >>= 1) m = fmaxf(m, __shfl_xor(m, o));
    const float p = expf(v - m);
    float ss = p;
    #pragma unroll
    for (int o = 32; o > 0; o >>= 1) ss += __shfl_xor(ss, o);
    const float score = p / ss;
    float cur = v + bias;
    float wk[TOPK]; int ik[TOPK]; float wsum = 0.f;
    #pragma unroll
    for (int k = 0; k < TOPK; ++k) {
      float tm = cur;
      #pragma unroll
      for (int o = 32; o > 0; o >>= 1) tm = fmaxf(tm, __shfl_xor(tm, o));
      const unsigned long long msk = __ballot(cur == tm);
      const int sel = (int)__builtin_ctzll(msk);
      const float w = __shfl(score, sel);
      wk[k] = w; ik[k] = sel; wsum += w;
      if (lane == sel) cur = -3.4e38f;
    }
    if (lane < TOPK) {
      const int e = ik[lane];
      const float w = wk[lane] / wsum;
      const int slot = atomicAdd(&cnt[e], 1);
      listTok[(size_t)e * N_TOK + slot] = token;
      listW[(size_t)e * N_TOK + slot] = w;
      tokEP[token * TOPK + lane] = (e << 16) | slot;
    }
  }
}

__global__ void scan_kernel(const int* __restrict__ cnt, int* __restrict__ off) {
  if (threadIdx.x == 0) {
    int s = 0;
    for (int e = 0; e < NEXP; ++e) { off[e] = s; s += cnt[e]; }
  }
}

// ---------------- Shared up (fused U+G): BM=128, BN=64(x2 mats), BK=64, bf16, single-buf ----------------
__global__ __launch_bounds__(256, 4)
void up_shared(const unsigned short* __restrict__ xb,
               const unsigned short* __restrict__ WuT, const unsigned short* __restrict__ WgT,
               unsigned short* __restrict__ H) {
  constexpr int NT = DIM / 64;  // 32
  const int tid = threadIdx.x;
  const int f0 = blockIdx.x * 64;
  const int s  = blockIdx.y;
  const int m0 = blockIdx.z * 128;

  __shared__ __align__(16) unsigned short Al[8][128][8];   // 16 KB
  __shared__ __align__(16) unsigned short BuL[8][64][8];   //  8 KB
  __shared__ __align__(16) unsigned short BgL[8][64][8];   //  8 KB

  const int wid = tid >> 6, l = tid & 63;
  const int lc = l & 15, hi = l >> 4;

  const unsigned short* pa0 = xb + (size_t)(m0 + l) * DIM;
  const unsigned short* pa1 = xb + (size_t)(m0 + 64 + l) * DIM;
  const unsigned short* pbu = WuT + (size_t)s * HSH * DIM + (size_t)(f0 + l) * DIM;
  const unsigned short* pbg = WgT + (size_t)s * HSH * DIM + (size_t)(f0 + l) * DIM;

  f32x4 aU[2][4], aG[2][4];
  #pragma unroll
  for (int i = 0; i < 2; ++i)
    #pragma unroll
    for (int j = 0; j < 4; ++j) { aU[i][j] = f32x4{0,0,0,0}; aG[i][j] = f32x4{0,0,0,0}; }

  for (int g = 0; g < NT; ++g) {
    const int d0 = g * 64;
    #pragma unroll
    for (int i = 0; i < 4; ++i) {           // A: 16 wave-loads total
      const int idx = wid * 4 + i;
      const int p = idx >> 1, hf = idx & 1;
      gll16((hf ? pa1 : pa0) + d0 + p * 8, &Al[p][hf * 64][0]);
    }
    #pragma unroll
    for (int i = 0; i < 2; ++i) {           // B: 8+8 wave-loads total
      const int p = wid * 2 + i;
      gll16(pbu + d0 + p * 8, &BuL[p][0][0]);
      gll16(pbg + d0 + p * 8, &BgL[p][0][0]);
    }
    __syncthreads();
    #pragma unroll
    for (int ks = 0; ks < 2; ++ks) {
      bf16x8 af[2], bu[4], bg[4];
      #pragma unroll
      for (int mi = 0; mi < 2; ++mi)
        af[mi] = *reinterpret_cast<const bf16x8*>(&Al[ks * 4 + hi][wid * 32 + mi * 16 + lc][0]);
      #pragma unroll
      for (int ni = 0; ni < 4; ++ni) {
        bu[ni] = *reinterpret_cast<const bf16x8*>(&BuL[ks * 4 + hi][ni * 16 + lc][0]);
        bg[ni] = *reinterpret_cast<const bf16x8*>(&BgL[ks * 4 + hi][ni * 16 + lc][0]);
      }
      #pragma unroll
      for (int mi = 0; mi < 2; ++mi)
        #pragma unroll
        for (int ni = 0; ni < 4; ++ni) {
          aU[mi][ni] = __builtin_amdgcn_mfma_f32_16x16x32_bf16(af[mi], bu[ni], aU[mi][ni], 0, 0, 0);
          aG[mi][ni] = __builtin_amdgcn_mfma_f32_16x16x32_bf16(af[mi], bg[ni], aG[mi][ni], 0, 0, 0);
        }
    }
    __syncthreads();
  }

  #pragma unroll
  for (int mi = 0; mi < 2; ++mi)
    #pragma unroll
    for (int ni = 0; ni < 4; ++ni)
      #pragma unroll
      for (int r2 = 0; r2 < 4; ++r2) {
        const int row = wid * 32 + mi * 16 + hi * 4 + r2;
        const int col = f0 + ni * 16 + lc;
        const float g = aG[mi][ni][r2], u = aU[mi][ni][r2];
        H[((size_t)s * N_TOK + m0 + row) * HSH + col] = f2b((g / (1.f + __expf(-g))) * u);
      }
}

// ---------------- Shared down: BM=128, BN=128, K-split x4 -> bf16 partials ----------------
__global__ __launch_bounds__(256, 4)
void down_shared(const unsigned short* __restrict__ Hs, const unsigned short* __restrict__ swdT,
                 unsigned short* __restrict__ shP) {
  constexpr int NT = 16;  // K-chunk 1024
  const int tid = threadIdx.x;
  const int x0 = blockIdx.x * 128;
  const int kc = blockIdx.y;            // 0..3
  const int m0 = blockIdx.z * 128;
  const int seg = kc >> 1;
  const int kb = (kc & 1) * 1024;

  __shared__ __align__(16) unsigned short Al[8][128][8];   // 16 KB
  __shared__ __align__(16) unsigned short Bl[8][128][8];   // 16 KB

  const int wid = tid >> 6, l = tid & 63;
  const int lc = l & 15, hi = l >> 4;

  const unsigned short* pa0 = Hs + ((size_t)seg * N_TOK + m0 + l) * HSH + kb;
  const unsigned short* pa1 = Hs + ((size_t)seg * N_TOK + m0 + 64 + l) * HSH + kb;
  const unsigned short* pb0 = swdT + (size_t)seg * HSH * DIM + (size_t)(x0 + l) * HSH + kb;
  const unsigned short* pb1 = swdT + (size_t)seg * HSH * DIM + (size_t)(x0 + 64 + l) * HSH + kb;

  f32x4 acc[2][8];
  #pragma unroll
  for (int i = 0; i < 2; ++i)
    #pragma unroll
    for (int j = 0; j < 8; ++j) acc[i][j] = f32x4{0,0,0,0};

  for (int g = 0; g < NT; ++g) {
    const int d0 = g * 64;
    #pragma unroll
    for (int i = 0; i < 4; ++i) {
      const int idx = wid * 4 + i;
      const int p = idx >> 1, hf = idx & 1;
      gll16((hf ? pa1 : pa0) + d0 + p * 8, &Al[p][hf * 64][0]);
      gll16((hf ? pb1 : pb0) + d0 + p * 8, &Bl[p][hf * 64][0]);
    }
    __syncthreads();
    #pragma unroll
    for (int ks = 0; ks < 2; ++ks) {
      bf16x8 af[2], bq[8];
      #pragma unroll
      for (int mi = 0; mi < 2; ++mi)
        af[mi] = *reinterpret_cast<const bf16x8*>(&Al[ks * 4 + hi][wid * 32 + mi * 16 + lc][0]);
      #pragma unroll
      for (int ni = 0; ni < 8; ++ni)
        bq[ni] = *reinterpret_cast<const bf16x8*>(&Bl[ks * 4 + hi][ni * 16 + lc][0]);
      #pragma unroll
      for (int mi = 0; mi < 2; ++mi)
        #pragma unroll
        for (int ni = 0; ni < 8; ++ni)
          acc[mi][ni] = __builtin_amdgcn_mfma_f32_16x16x32_bf16(af[mi], bq[ni], acc[mi][ni], 0, 0, 0);
    }
    __syncthreads();
  }

  unsigned short* pout = shP + (size_t)kc * N_TOK * DIM;
  #pragma unroll
  for (int mi = 0; mi < 2; ++mi)
    #pragma unroll
    for (int ni = 0; ni < 8; ++ni)
      #pragma unroll
      for (int r2 = 0; r2 < 4; ++r2) {
        const int row = wid * 32 + mi * 16 + hi * 4 + r2;
        const int col = x0 + ni * 16 + lc;
        pout[(size_t)(m0 + row) * DIM + col] = f2b(acc[mi][ni][r2]);
      }
}

// ---------------- Routed up, split passes: GPASS=0 -> H=U; GPASS=1 -> H=silu(G)*U*w ----------------
// BM=256, BN=64, BK=64; LDS 48KB -> 3 blocks/CU; acc 64 VGPR (no spill at (256,3)).
template<bool GPASS>
__global__ __launch_bounds__(256, 3)
void up_routed(const unsigned short* __restrict__ xb, const float* __restrict__ W,
               const int* __restrict__ cnt, const int* __restrict__ off,
               const int* __restrict__ listTok, const float* __restrict__ listW,
               unsigned short* __restrict__ H) {
  constexpr int NT = DIM / 64;  // 32
  const int tid = threadIdx.x;
  const int f0 = blockIdx.x * 64;
  const int e  = blockIdx.y;
  const int m0 = blockIdx.z * 256;
  const int c = cnt[e];
  if (m0 >= c) return;
  const int rc = min(256, c - m0);
  const int rowbase = off[e] + m0;

  __shared__ __align__(16) unsigned short Al[8][256][8];   // 32 KB
  __shared__ __align__(16) float Bf[64][64];               // 16 KB
  __shared__ float wSs[256];

  if (GPASS) wSs[tid] = (m0 + tid < c) ? listW[(size_t)e * N_TOK + m0 + tid] : 0.f;

  const int wid = tid >> 6, l = tid & 63;
  const int lc = l & 15, hi = l >> 4;

  const unsigned short* pa[4];
  #pragma unroll
  for (int j = 0; j < 4; ++j) {
    const int tok = listTok[(size_t)e * N_TOK + min(m0 + j * 64 + l, c - 1)];
    pa[j] = xb + (size_t)tok * DIM;
  }
  const float* pw = W + (size_t)e * DIM * FDIM + (size_t)(l >> 4) * FDIM + f0 + (l & 15) * 4;

  f32x4 acc[4][4];
  #pragma unroll
  for (int i = 0; i < 4; ++i)
    #pragma unroll
    for (int j = 0; j < 4; ++j) acc[i][j] = f32x4{0,0,0,0};

  for (int g = 0; g < NT; ++g) {
    const int d0 = g * 64;
    #pragma unroll
    for (int i = 0; i < 8; ++i) {           // A: 32 wave-loads
      const int idx = wid * 8 + i;
      const int p = idx >> 2, j = idx & 3;
      gll16(pa[j] + d0 + p * 8, &Al[p][j * 64][0]);
    }
    #pragma unroll
    for (int i = 0; i < 4; ++i) {           // B: 16 wave-loads (4 k-rows each)
      const int krow = (wid * 4 + i) * 4;
      gll16(pw + (size_t)(d0 + krow) * FDIM, &Bf[krow][0]);
    }
    __syncthreads();
    #pragma unroll
    for (int ks = 0; ks < 2; ++ks) {
      bf16x8 af[4];
      #pragma unroll
      for (int mi = 0; mi < 4; ++mi)
        af[mi] = *reinterpret_cast<const bf16x8*>(&Al[ks * 4 + hi][wid * 64 + mi * 16 + lc][0]);
      #pragma unroll
      for (int ni = 0; ni < 4; ++ni) {
        const bf16x8 bq = fragB(&Bf[ks * 32 + hi * 8][ni * 16 + lc], 64);
        #pragma unroll
        for (int mi = 0; mi < 4; ++mi)
          acc[mi][ni] = __builtin_amdgcn_mfma_f32_16x16x32_bf16(af[mi], bq, acc[mi][ni], 0, 0, 0);
      }
    }
    __syncthreads();
  }

  #pragma unroll
  for (int mi = 0; mi < 4; ++mi)
    #pragma unroll
    for (int ni = 0; ni < 4; ++ni)
      #pragma unroll
      for (int r2 = 0; r2 < 4; ++r2) {
        const int row = wid * 64 + mi * 16 + hi * 4 + r2;
        if (row < rc) {
          const int col = f0 + ni * 16 + lc;
          const size_t idx = (size_t)(rowbase + row) * FDIM + col;
          const float v = acc[mi][ni][r2];
          if (GPASS) {
            const float u = b2f(H[idx]);
            H[idx] = f2b((v / (1.f + __expf(-v))) * u * wSs[row]);
          } else {
            H[idx] = f2b(v);
          }
        }
      }
}

// ---------------- Routed down: BM=256, BN=64, BK=64, f32 B via gll16+fragB -> P ----------------
__global__ __launch_bounds__(256, 3)
void down_routed(const unsigned short* __restrict__ Hr, const float* __restrict__ wd,
                 const int* __restrict__ cnt, const int* __restrict__ off,
                 unsigned short* __restrict__ P) {
  constexpr int NT = FDIM / 64;  // 8
  const int tid = threadIdx.x;
  const int x0 = blockIdx.x * 64;
  const int e  = blockIdx.y;
  const int m0 = blockIdx.z * 256;
  const int c = cnt[e];
  if (m0 >= c) return;
  const int rc = min(256, c - m0);
  const int rowbase = off[e] + m0;

  __shared__ __align__(16) unsigned short Al[8][256][8];   // 32 KB
  __shared__ __align__(16) float Bf[64][64];               // 16 KB

  const int wid = tid >> 6, l = tid & 63;
  const int lc = l & 15, hi = l >> 4;

  const unsigned short* pa[4];
  #pragma unroll
  for (int j = 0; j < 4; ++j)
    pa[j] = Hr + (size_t)(rowbase + min(j * 64 + l, c - m0 - 1)) * FDIM;

  const float* pwd = wd + (size_t)e * FDIM * DIM + (size_t)(l >> 4) * DIM + x0 + (l & 15) * 4;

  f32x4 acc[4][4];
  #pragma unroll
  for (int i = 0; i < 4; ++i)
    #pragma unroll
    for (int j = 0; j < 4; ++j) acc[i][j] = f32x4{0,0,0,0};

  for (int g = 0; g < NT; ++g) {
    const int d0 = g * 64;
    #pragma unroll
    for (int i = 0; i < 8; ++i) {           // A: 32 wave-loads
      const int idx = wid * 8 + i;
      const int p = idx >> 2, j = idx & 3;
      gll16(pa[j] + d0 + p * 8, &Al[p][j * 64][0]);
    }
    #pragma unroll
    for (int i = 0; i < 4; ++i) {           // B: 16 wave-loads (4 k-rows each)
      const int krow = (wid * 4 + i) * 4;
      gll16(pwd + (size_t)(d0 + krow) * DIM, &Bf[krow][0]);
    }
    __syncthreads();
    #pragma unroll
    for (int ks = 0; ks < 2; ++ks) {
      bf16x8 af[4];
      #pragma unroll
      for (int mi = 0; mi < 4; ++mi)
        af[mi] = *reinterpret_cast<const bf16x8*>(&Al[ks * 4 + hi][wid * 64 + mi * 16 + lc][0]);
      #pragma unroll
      for (int ni = 0; ni < 4; ++ni) {
        const bf16x8 bq = fragB(&Bf[ks * 32 + hi * 8][ni * 16 + lc], 64);
        #pragma unroll
        for (int mi = 0; mi < 4; ++mi)
          acc[mi][ni] = __builtin_amdgcn_mfma_f32_16x16x32_bf16(af[mi], bq, acc[mi][ni], 0, 0, 0);
      }
    }
    __syncthreads();
  }

  #pragma unroll
  for (int mi = 0; mi < 4; ++mi)
    #pragma unroll
    for (int ni = 0; ni < 4; ++ni)
      #pragma unroll
      for (int r2 = 0; r2 < 4; ++r2) {
        const int row = wid * 64 + mi * 16 + hi * 4 + r2;
        if (row < rc) {
          const int col = x0 + ni * 16 + lc;
          P[(size_t)(rowbase + row) * DIM + col] = f2b(acc[mi][ni][r2]);
        }
      }
}

// ---------------- Combine: out[n] = sum_k routedP[slot(n,k)] + sum_j shP[j][n] ----------------
__global__ __launch_bounds__(256)
void combine_kernel(const int* __restrict__ tokEP, const int* __restrict__ off,
                    const unsigned short* __restrict__ P, const unsigned short* __restrict__ shP,
                    float* __restrict__ out) {
  const int n = blockIdx.x;
  const int tid = threadIdx.x;
  int rows[4];
  #pragma unroll
  for (int k = 0; k < TOPK; ++k) {
    const int ep = tokEP[n * TOPK + k];
    rows[k] = off[ep >> 16] + (ep & 0xffff);
  }
  const int cc = tid * 8;
  float4 o0 = {0, 0, 0, 0}, o1 = {0, 0, 0, 0};
  #pragma unroll
  for (int k = 0; k < TOPK; ++k) {
    const u16x8 v = *reinterpret_cast<const u16x8*>(P + (size_t)rows[k] * DIM + cc);
    o0.x += b2f(v[0]); o0.y += b2f(v[1]); o0.z += b2f(v[2]); o0.w += b2f(v[3]);
    o1.x += b2f(v[4]); o1.y += b2f(v[5]); o1.z += b2f(v[6]); o1.w += b2f(v[7]);
  }
  #pragma unroll
  for (int j = 0; j < 4; ++j) {
    const u16x8 v = *reinterpret_cast<const u16x8*>(shP + ((size_t)j * N_TOK + n) * DIM + cc);
    o0.x += b2f(v[0]); o0.y += b2f(v[1]); o0.z += b2f(v[2]); o0.w += b2f(v[3]);
    o1.x += b2f(v[4]); o1.y += b2f(v[5]); o1.z += b2f(v[6]); o1.w += b2f(v[7]);
  }
  float* po = out + (size_t)n * DIM + cc;
  *reinterpret_cast<float4*>(po) = o0;
  *reinterpret_cast<float4*>(po + 4) = o1;
}

extern "C" void kernel_launch(void* const* d_in, const int* in_sizes, int n_in,
                              void* d_out, int out_size, void* d_ws, size_t ws_size,
                              hipStream_t stream) {
  const float* x   = (const float*)d_in[0];
  const float* rw  = (const float*)d_in[1];
  const float* rb  = (const float*)d_in[2];
  const float* wg  = (const float*)d_in[3];
  const float* wu  = (const float*)d_in[4];
  const float* wd  = (const float*)d_in[5];
  const float* swg = (const float*)d_in[6];
  const float* swu = (const float*)d_in[7];
  const float* swd = (const float*)d_in[8];
  float* out = (float*)d_out;
  char* ws = (char*)d_ws;

  int* cnt = (int*)ws;
  int* off = (int*)(ws + 256);
  int* tokEP = (int*)(ws + 4096);
  int* listTok = (int*)(ws + 64 * 1024);
  float* listW = (float*)(ws + 576 * 1024);
  unsigned short* xb   = (unsigned short*)(ws + (size_t) 2 * 1024 * 1024);  //  8 MB
  unsigned short* Hr   = (unsigned short*)(ws + (size_t)10 * 1024 * 1024);  //  8 MB
  unsigned short* Hs   = (unsigned short*)(ws + (size_t)18 * 1024 * 1024);  // 16 MB
  unsigned short* swuT = (unsigned short*)(ws + (size_t)34 * 1024 * 1024);  // 16 MB
  unsigned short* swgT = (unsigned short*)(ws + (size_t)50 * 1024 * 1024);  // 16 MB
  unsigned short* swdT = (unsigned short*)(ws + (size_t)66 * 1024 * 1024);  // 16 MB
  unsigned short* P    = (unsigned short*)(ws + (size_t)82 * 1024 * 1024);  // 32 MB
  // shP aliases swuT+swgT (32 MB) — dead after up_shared completes (stream-serial).
  unsigned short* shP  = swuT;

  hipMemsetAsync(cnt, 0, NEXP * sizeof(int), stream);
  cvt_x_kernel<<<(N_TOK * DIM) / (256 * 8), 256, 0, stream>>>(x, xb);
  router_kernel<<<N_TOK / 8, 256, 0, stream>>>(x, rw, rb, cnt, listTok, listW, tokEP);
  scan_kernel<<<1, 64, 0, stream>>>(cnt, off);
  tr_shared_kernel<<<dim3(32, 32, 6), 256, 0, stream>>>(swu, swg, swd, swuT, swgT, swdT);

  up_shared<<<dim3(HSH / 64, NSH, N_TOK / 128), 256, 0, stream>>>(xb, swuT, swgT, Hs);
  up_routed<false><<<dim3(FDIM / 64, NEXP, 8), 256, 0, stream>>>(xb, wu, cnt, off, listTok, listW, Hr);
  up_routed<true ><<<dim3(FDIM / 64, NEXP, 8), 256, 0, stream>>>(xb, wg, cnt, off, listTok, listW, Hr);
  down_shared<<<dim3(DIM / 128, 4, N_TOK / 128), 256, 0, stream>>>(Hs, swdT, shP);
  down_routed<<<dim3(DIM / 64, NEXP, 8), 256, 0, stream>>>(Hr, wd, cnt, off, P);
  combine_kernel<<<N_TOK, 256, 0, stream>>>(tokEP, off, P, shP, out);
}

// Round 15
// 611.460 us; speedup vs baseline: 1.6063x; 1.0521x over previous
//
#include <hip/hip_runtime.h>
#include <hip/hip_bf16.h>

typedef __bf16 bf16x8 __attribute__((ext_vector_type(8)));
typedef float f32x4 __attribute__((ext_vector_type(4)));
typedef unsigned short u16x4 __attribute__((ext_vector_type(4)));
typedef unsigned short u16x8 __attribute__((ext_vector_type(8)));

#define DEVI __device__ __forceinline__

constexpr int N_TOK = 2048;
constexpr int DIM   = 2048;
constexpr int NEXP  = 64;
constexpr int FDIM  = 512;
constexpr int TOPK  = 4;
constexpr int NSH   = 2;
constexpr int HSH   = 2048;

DEVI unsigned short f2b(float f) {
  union { float fv; unsigned u; } v; v.fv = f;
  unsigned r = v.u + 0x7fffu + ((v.u >> 16) & 1u);
  return (unsigned short)(r >> 16);
}
DEVI float b2f(unsigned short h) {
  union { unsigned u; float f; } v; v.u = ((unsigned)h) << 16;
  return v.f;
}
DEVI void gll16(const void* g, void* l) {
  __builtin_amdgcn_global_load_lds((const __attribute__((address_space(1))) unsigned*)g,
                                   (__attribute__((address_space(3))) unsigned*)l, 16, 0, 0);
}
DEVI unsigned cvtpk(float lo, float hi) {
  unsigned r;
  asm("v_cvt_pk_bf16_f32 %0, %1, %2" : "=v"(r) : "v"(lo), "v"(hi));
  return r;
}
// bf16x8 B-fragment from f32 LDS tile, 8 consecutive k rows at one column; row stride str floats.
DEVI bf16x8 fragB(const float* base, int str) {
  union { unsigned u[4]; bf16x8 v; } r;
  #pragma unroll
  for (int p = 0; p < 4; ++p) r.u[p] = cvtpk(base[(2 * p) * str], base[(2 * p + 1) * str]);
  return r.v;
}

// ---------------- x -> bf16 ----------------
__global__ void cvt_x_kernel(const float* __restrict__ x, unsigned short* __restrict__ xb) {
  const size_t i = ((size_t)blockIdx.x * 256 + threadIdx.x) * 8;
  const float4 a = *reinterpret_cast<const float4*>(x + i);
  const float4 b = *reinterpret_cast<const float4*>(x + i + 4);
  u16x8 o;
  o[0] = f2b(a.x); o[1] = f2b(a.y); o[2] = f2b(a.z); o[3] = f2b(a.w);
  o[4] = f2b(b.x); o[5] = f2b(b.y); o[6] = f2b(b.z); o[7] = f2b(b.w);
  *reinterpret_cast<u16x8*>(xb + i) = o;
}

// ---------------- shared weights: transpose + bf16 ----------------
__global__ __launch_bounds__(256)
void tr_shared_kernel(const float* __restrict__ swu, const float* __restrict__ swg,
                      const float* __restrict__ swd, unsigned short* __restrict__ swuT,
                      unsigned short* __restrict__ swgT, unsigned short* __restrict__ swdT) {
  __shared__ float Lf[64][68];
  const int tid = threadIdx.x;
  const int r0 = blockIdx.x * 64, c0 = blockIdx.y * 64;
  const int z = blockIdx.z, mat = z >> 1;
  const size_t soff = (size_t)(z & 1) * DIM * HSH;
  const float* in = (mat == 0 ? swu : mat == 1 ? swg : swd) + soff;
  unsigned short* ot = (mat == 0 ? swuT : mat == 1 ? swgT : swdT) + soff;
  #pragma unroll
  for (int j = 0; j < 4; ++j) {
    const int idx = j * 1024 + tid * 4;
    const int row = idx >> 6, col = idx & 63;
    const float4 v = *reinterpret_cast<const float4*>(in + (size_t)(r0 + row) * 2048 + c0 + col);
    *reinterpret_cast<float4*>(&Lf[row][col]) = v;
  }
  __syncthreads();
  #pragma unroll
  for (int j = 0; j < 4; ++j) {
    const int idx = j * 1024 + tid * 4;
    const int orow = idx >> 6, ocol = idx & 63;
    u16x4 o;
    o[0] = f2b(Lf[ocol][orow]);     o[1] = f2b(Lf[ocol + 1][orow]);
    o[2] = f2b(Lf[ocol + 2][orow]); o[3] = f2b(Lf[ocol + 3][orow]);
    *reinterpret_cast<u16x4*>(ot + (size_t)(c0 + orow) * 2048 + r0 + ocol) = o;
  }
}

// ---------------- Router ----------------
__global__ __launch_bounds__(256)
void router_kernel(const float* __restrict__ x, const float* __restrict__ rw,
                   const float* __restrict__ rb, int* __restrict__ cnt,
                   int* __restrict__ listTok, float* __restrict__ listW,
                   int* __restrict__ tokEP) {
  __shared__ float Lx[8][128];
  const int tid = threadIdx.x;
  const int lane = tid & 63;
  const int wave = tid >> 6;
  const int tokBase = blockIdx.x * 8;

  float acc0 = 0.f, acc1 = 0.f;
  for (int dc = 0; dc < DIM; dc += 128) {
    __syncthreads();
    {
      const int idx = tid * 4;
      const int row = idx >> 7, col = idx & 127;
      *reinterpret_cast<float4*>(&Lx[row][col]) =
          *reinterpret_cast<const float4*>(x + (size_t)(tokBase + row) * DIM + dc + col);
    }
    __syncthreads();
    #pragma unroll 16
    for (int dd = 0; dd < 128; ++dd) {
      const float r = rw[(size_t)(dc + dd) * NEXP + lane];
      acc0 = fmaf(Lx[wave * 2 + 0][dd], r, acc0);
      acc1 = fmaf(Lx[wave * 2 + 1][dd], r, acc1);
    }
  }

  const float bias = rb[lane];
  #pragma unroll
  for (int t = 0; t < 2; ++t) {
    const float v = (t == 0) ? acc0 : acc1;
    const int token = tokBase + wave * 2 + t;
    float m = v;
    #pragma unroll
    for (int o = 32; o > 0; o >>= 1) m = fmaxf(m, __shfl_xor(m, o));
    const float p = expf(v - m);
    float ss = p;
    #pragma unroll
    for (int o = 32; o > 0; o >>= 1) ss += __shfl_xor(ss, o);
    const float score = p / ss;
    float cur = v + bias;
    float wk[TOPK]; int ik[TOPK]; float wsum = 0.f;
    #pragma unroll
    for (int k = 0; k < TOPK; ++k) {
      float tm = cur;
      #pragma unroll
      for (int o = 32; o > 0; o >>= 1) tm = fmaxf(tm, __shfl_xor(tm, o));
      const unsigned long long msk = __ballot(cur == tm);
      const int sel = (int)__builtin_ctzll(msk);
      const float w = __shfl(score, sel);
      wk[k] = w; ik[k] = sel; wsum += w;
      if (lane == sel) cur = -3.4e38f;
    }
    if (lane < TOPK) {
      const int e = ik[lane];
      const float w = wk[lane] / wsum;
      const int slot = atomicAdd(&cnt[e], 1);
      listTok[(size_t)e * N_TOK + slot] = token;
      listW[(size_t)e * N_TOK + slot] = w;
      tokEP[token * TOPK + lane] = (e << 16) | slot;
    }
  }
}

__global__ void scan_kernel(const int* __restrict__ cnt, int* __restrict__ off) {
  if (threadIdx.x == 0) {
    int s = 0;
    for (int e = 0; e < NEXP; ++e) { off[e] = s; s += cnt[e]; }
  }
}

// ---------------- Shared up (fused U+G): BM=128, BN=64(x2 mats), BK=64, bf16, single-buf ----------------
__global__ __launch_bounds__(256, 4)
void up_shared(const unsigned short* __restrict__ xb,
               const unsigned short* __restrict__ WuT, const unsigned short* __restrict__ WgT,
               unsigned short* __restrict__ H) {
  constexpr int NT = DIM / 64;  // 32
  const int tid = threadIdx.x;
  const int f0 = blockIdx.x * 64;
  const int s  = blockIdx.y;
  const int m0 = blockIdx.z * 128;

  __shared__ __align__(16) unsigned short Al[8][128][8];   // 16 KB
  __shared__ __align__(16) unsigned short BuL[8][64][8];   //  8 KB
  __shared__ __align__(16) unsigned short BgL[8][64][8];   //  8 KB

  const int wid = tid >> 6, l = tid & 63;
  const int lc = l & 15, hi = l >> 4;

  const unsigned short* pa0 = xb + (size_t)(m0 + l) * DIM;
  const unsigned short* pa1 = xb + (size_t)(m0 + 64 + l) * DIM;
  const unsigned short* pbu = WuT + (size_t)s * HSH * DIM + (size_t)(f0 + l) * DIM;
  const unsigned short* pbg = WgT + (size_t)s * HSH * DIM + (size_t)(f0 + l) * DIM;

  f32x4 aU[2][4], aG[2][4];
  #pragma unroll
  for (int i = 0; i < 2; ++i)
    #pragma unroll
    for (int j = 0; j < 4; ++j) { aU[i][j] = f32x4{0,0,0,0}; aG[i][j] = f32x4{0,0,0,0}; }

  for (int g = 0; g < NT; ++g) {
    const int d0 = g * 64;
    #pragma unroll
    for (int i = 0; i < 4; ++i) {           // A: 16 wave-loads total
      const int idx = wid * 4 + i;
      const int p = idx >> 1, hf = idx & 1;
      gll16((hf ? pa1 : pa0) + d0 + p * 8, &Al[p][hf * 64][0]);
    }
    #pragma unroll
    for (int i = 0; i < 2; ++i) {           // B: 8+8 wave-loads total
      const int p = wid * 2 + i;
      gll16(pbu + d0 + p * 8, &BuL[p][0][0]);
      gll16(pbg + d0 + p * 8, &BgL[p][0][0]);
    }
    __syncthreads();
    #pragma unroll
    for (int ks = 0; ks < 2; ++ks) {
      bf16x8 af[2], bu[4], bg[4];
      #pragma unroll
      for (int mi = 0; mi < 2; ++mi)
        af[mi] = *reinterpret_cast<const bf16x8*>(&Al[ks * 4 + hi][wid * 32 + mi * 16 + lc][0]);
      #pragma unroll
      for (int ni = 0; ni < 4; ++ni) {
        bu[ni] = *reinterpret_cast<const bf16x8*>(&BuL[ks * 4 + hi][ni * 16 + lc][0]);
        bg[ni] = *reinterpret_cast<const bf16x8*>(&BgL[ks * 4 + hi][ni * 16 + lc][0]);
      }
      #pragma unroll
      for (int mi = 0; mi < 2; ++mi)
        #pragma unroll
        for (int ni = 0; ni < 4; ++ni) {
          aU[mi][ni] = __builtin_amdgcn_mfma_f32_16x16x32_bf16(af[mi], bu[ni], aU[mi][ni], 0, 0, 0);
          aG[mi][ni] = __builtin_amdgcn_mfma_f32_16x16x32_bf16(af[mi], bg[ni], aG[mi][ni], 0, 0, 0);
        }
    }
    __syncthreads();
  }

  #pragma unroll
  for (int mi = 0; mi < 2; ++mi)
    #pragma unroll
    for (int ni = 0; ni < 4; ++ni)
      #pragma unroll
      for (int r2 = 0; r2 < 4; ++r2) {
        const int row = wid * 32 + mi * 16 + hi * 4 + r2;
        const int col = f0 + ni * 16 + lc;
        const float g = aG[mi][ni][r2], u = aU[mi][ni][r2];
        H[((size_t)s * N_TOK + m0 + row) * HSH + col] = f2b((g / (1.f + __expf(-g))) * u);
      }
}

// ---------------- Shared down: BM=128, BN=128, K-split x4 -> bf16 partials ----------------
__global__ __launch_bounds__(256, 4)
void down_shared(const unsigned short* __restrict__ Hs, const unsigned short* __restrict__ swdT,
                 unsigned short* __restrict__ shP) {
  constexpr int NT = 16;  // K-chunk 1024
  const int tid = threadIdx.x;
  const int x0 = blockIdx.x * 128;
  const int kc = blockIdx.y;            // 0..3
  const int m0 = blockIdx.z * 128;
  const int seg = kc >> 1;
  const int kb = (kc & 1) * 1024;

  __shared__ __align__(16) unsigned short Al[8][128][8];   // 16 KB
  __shared__ __align__(16) unsigned short Bl[8][128][8];   // 16 KB

  const int wid = tid >> 6, l = tid & 63;
  const int lc = l & 15, hi = l >> 4;

  const unsigned short* pa0 = Hs + ((size_t)seg * N_TOK + m0 + l) * HSH + kb;
  const unsigned short* pa1 = Hs + ((size_t)seg * N_TOK + m0 + 64 + l) * HSH + kb;
  const unsigned short* pb0 = swdT + (size_t)seg * HSH * DIM + (size_t)(x0 + l) * HSH + kb;
  const unsigned short* pb1 = swdT + (size_t)seg * HSH * DIM + (size_t)(x0 + 64 + l) * HSH + kb;

  f32x4 acc[2][8];
  #pragma unroll
  for (int i = 0; i < 2; ++i)
    #pragma unroll
    for (int j = 0; j < 8; ++j) acc[i][j] = f32x4{0,0,0,0};

  for (int g = 0; g < NT; ++g) {
    const int d0 = g * 64;
    #pragma unroll
    for (int i = 0; i < 4; ++i) {
      const int idx = wid * 4 + i;
      const int p = idx >> 1, hf = idx & 1;
      gll16((hf ? pa1 : pa0) + d0 + p * 8, &Al[p][hf * 64][0]);
      gll16((hf ? pb1 : pb0) + d0 + p * 8, &Bl[p][hf * 64][0]);
    }
    __syncthreads();
    #pragma unroll
    for (int ks = 0; ks < 2; ++ks) {
      bf16x8 af[2], bq[8];
      #pragma unroll
      for (int mi = 0; mi < 2; ++mi)
        af[mi] = *reinterpret_cast<const bf16x8*>(&Al[ks * 4 + hi][wid * 32 + mi * 16 + lc][0]);
      #pragma unroll
      for (int ni = 0; ni < 8; ++ni)
        bq[ni] = *reinterpret_cast<const bf16x8*>(&Bl[ks * 4 + hi][ni * 16 + lc][0]);
      #pragma unroll
      for (int mi = 0; mi < 2; ++mi)
        #pragma unroll
        for (int ni = 0; ni < 8; ++ni)
          acc[mi][ni] = __builtin_amdgcn_mfma_f32_16x16x32_bf16(af[mi], bq[ni], acc[mi][ni], 0, 0, 0);
    }
    __syncthreads();
  }

  unsigned short* pout = shP + (size_t)kc * N_TOK * DIM;
  #pragma unroll
  for (int mi = 0; mi < 2; ++mi)
    #pragma unroll
    for (int ni = 0; ni < 8; ++ni)
      #pragma unroll
      for (int r2 = 0; r2 < 4; ++r2) {
        const int row = wid * 32 + mi * 16 + hi * 4 + r2;
        const int col = x0 + ni * 16 + lc;
        pout[(size_t)(m0 + row) * DIM + col] = f2b(acc[mi][ni][r2]);
      }
}

// ---------------- Routed up (fused U+G): BM=256, BN=64(x2), BK=32, 2-phase dbuf ----------------
// LDS: A 2x16KB + B 2x(8+8)KB = 64KB -> 2 blocks/CU at (256,2). Stage(g+1) issued BEFORE
// compute(g); __syncthreads' implicit vmcnt(0) drains at iter end -> loads overlap compute.
__global__ __launch_bounds__(256, 2)
void up_routed(const unsigned short* __restrict__ xb,
               const float* __restrict__ Wu, const float* __restrict__ Wg,
               const int* __restrict__ cnt, const int* __restrict__ off,
               const int* __restrict__ listTok, const float* __restrict__ listW,
               unsigned short* __restrict__ H) {
  constexpr int NT = DIM / 32;  // 64
  const int tid = threadIdx.x;
  const int f0 = blockIdx.x * 64;
  const int e  = blockIdx.y;
  const int m0 = blockIdx.z * 256;
  const int c = cnt[e];
  if (m0 >= c) return;
  const int rc = min(256, c - m0);
  const int rowbase = off[e] + m0;

  __shared__ __align__(16) unsigned short Al[2][4][256][8];  // 32 KB
  __shared__ __align__(16) float Bfu[2][32][64];             // 16 KB
  __shared__ __align__(16) float Bfg[2][32][64];             // 16 KB
  __shared__ float wSs[256];

  wSs[tid] = (m0 + tid < c) ? listW[(size_t)e * N_TOK + m0 + tid] : 0.f;

  const int wid = tid >> 6, l = tid & 63;
  const int lc = l & 15, hi = l >> 4;

  const unsigned short* pa[4];
  #pragma unroll
  for (int j = 0; j < 4; ++j) {
    const int tok = listTok[(size_t)e * N_TOK + min(m0 + j * 64 + l, c - 1)];
    pa[j] = xb + (size_t)tok * DIM;
  }
  const float* pwu = Wu + (size_t)e * DIM * FDIM + (size_t)(l >> 4) * FDIM + f0 + (l & 15) * 4;
  const float* pwg = Wg + (size_t)e * DIM * FDIM + (size_t)(l >> 4) * FDIM + f0 + (l & 15) * 4;

  f32x4 aU[4][4], aG[4][4];
  #pragma unroll
  for (int i = 0; i < 4; ++i)
    #pragma unroll
    for (int j = 0; j < 4; ++j) { aU[i][j] = f32x4{0,0,0,0}; aG[i][j] = f32x4{0,0,0,0}; }

  auto stage = [&](int g, int b) {
    const int d0 = g * 32;
    // A: wave `wid` fills plane `wid` (4 wave-loads of 64 rows each)
    #pragma unroll
    for (int j = 0; j < 4; ++j)
      gll16(pa[j] + d0 + wid * 8, &Al[b][wid][j * 64][0]);
    // B: 8 wave-loads per mat (4 k-rows each); wave wid covers rows wid*8 .. wid*8+7
    #pragma unroll
    for (int i = 0; i < 2; ++i) {
      const int krow = (wid * 2 + i) * 4;
      gll16(pwu + (size_t)(d0 + krow) * FDIM, &Bfu[b][krow][0]);
      gll16(pwg + (size_t)(d0 + krow) * FDIM, &Bfg[b][krow][0]);
    }
  };

  stage(0, 0);
  __syncthreads();

  for (int g = 0; g < NT; ++g) {
    const int b = g & 1;
    if (g + 1 < NT) stage(g + 1, b ^ 1);
    bf16x8 af[4];
    #pragma unroll
    for (int mi = 0; mi < 4; ++mi)
      af[mi] = *reinterpret_cast<const bf16x8*>(&Al[b][hi][wid * 64 + mi * 16 + lc][0]);
    #pragma unroll
    for (int ni = 0; ni < 4; ++ni) {
      const bf16x8 bu = fragB(&Bfu[b][hi * 8][ni * 16 + lc], 64);
      const bf16x8 bg = fragB(&Bfg[b][hi * 8][ni * 16 + lc], 64);
      #pragma unroll
      for (int mi = 0; mi < 4; ++mi) {
        aU[mi][ni] = __builtin_amdgcn_mfma_f32_16x16x32_bf16(af[mi], bu, aU[mi][ni], 0, 0, 0);
        aG[mi][ni] = __builtin_amdgcn_mfma_f32_16x16x32_bf16(af[mi], bg, aG[mi][ni], 0, 0, 0);
      }
    }
    __syncthreads();
  }

  #pragma unroll
  for (int mi = 0; mi < 4; ++mi)
    #pragma unroll
    for (int ni = 0; ni < 4; ++ni)
      #pragma unroll
      for (int r2 = 0; r2 < 4; ++r2) {
        const int row = wid * 64 + mi * 16 + hi * 4 + r2;
        if (row < rc) {
          const int col = f0 + ni * 16 + lc;
          const float g = aG[mi][ni][r2], u = aU[mi][ni][r2];
          const float h = (g / (1.f + __expf(-g))) * u * wSs[row];
          H[(size_t)(rowbase + row) * FDIM + col] = f2b(h);
        }
      }
}

// ---------------- Routed down: BM=256, BN=128, K=512, f32 B via gll16+fragB -> P ----------------
__global__ __launch_bounds__(256, 2)
void down_routed(const unsigned short* __restrict__ Hr, const float* __restrict__ wd,
                 const int* __restrict__ cnt, const int* __restrict__ off,
                 unsigned short* __restrict__ P) {
  constexpr int NT = FDIM / 64;  // 8
  const int tid = threadIdx.x;
  const int x0 = blockIdx.x * 128;
  const int e  = blockIdx.y;
  const int m0 = blockIdx.z * 256;
  const int c = cnt[e];
  if (m0 >= c) return;
  const int rc = min(256, c - m0);
  const int rowbase = off[e] + m0;

  __shared__ __align__(16) unsigned short Al[8][256][8];   // 32 KB
  __shared__ __align__(16) float Bf[64][128];              // 32 KB

  const int wid = tid >> 6, l = tid & 63;
  const int lc = l & 15, hi = l >> 4;

  const unsigned short* pa[4];
  #pragma unroll
  for (int j = 0; j < 4; ++j)
    pa[j] = Hr + (size_t)(rowbase + min(j * 64 + l, c - m0 - 1)) * FDIM;

  const float* pwd = wd + (size_t)e * FDIM * DIM + (size_t)(l >> 5) * DIM + x0 + (l & 31) * 4;

  f32x4 acc[4][8];
  #pragma unroll
  for (int i = 0; i < 4; ++i)
    #pragma unroll
    for (int j = 0; j < 8; ++j) acc[i][j] = f32x4{0,0,0,0};

  for (int g = 0; g < NT; ++g) {
    const int d0 = g * 64;
    #pragma unroll
    for (int i = 0; i < 8; ++i) {           // A: 32 wave-loads
      const int idx = wid * 8 + i;
      const int p = idx >> 2, j = idx & 3;
      gll16(pa[j] + d0 + p * 8, &Al[p][j * 64][0]);
    }
    #pragma unroll
    for (int i = 0; i < 8; ++i) {           // B: 32 wave-loads (2 k-rows each)
      const int krow = (wid * 8 + i) * 2;
      gll16(pwd + (size_t)(d0 + krow) * DIM, &Bf[krow][0]);
    }
    __syncthreads();
    #pragma unroll
    for (int ks = 0; ks < 2; ++ks) {
      bf16x8 af[4];
      #pragma unroll
      for (int mi = 0; mi < 4; ++mi)
        af[mi] = *reinterpret_cast<const bf16x8*>(&Al[ks * 4 + hi][wid * 64 + mi * 16 + lc][0]);
      #pragma unroll
      for (int ni = 0; ni < 8; ++ni) {
        const bf16x8 bq = fragB(&Bf[ks * 32 + hi * 8][ni * 16 + lc], 128);
        #pragma unroll
        for (int mi = 0; mi < 4; ++mi)
          acc[mi][ni] = __builtin_amdgcn_mfma_f32_16x16x32_bf16(af[mi], bq, acc[mi][ni], 0, 0, 0);
      }
    }
    __syncthreads();
  }

  #pragma unroll
  for (int mi = 0; mi < 4; ++mi)
    #pragma unroll
    for (int ni = 0; ni < 8; ++ni)
      #pragma unroll
      for (int r2 = 0; r2 < 4; ++r2) {
        const int row = wid * 64 + mi * 16 + hi * 4 + r2;
        if (row < rc) {
          const int col = x0 + ni * 16 + lc;
          P[(size_t)(rowbase + row) * DIM + col] = f2b(acc[mi][ni][r2]);
        }
      }
}

// ---------------- Combine: out[n] = sum_k routedP[slot(n,k)] + sum_j shP[j][n] ----------------
__global__ __launch_bounds__(256)
void combine_kernel(const int* __restrict__ tokEP, const int* __restrict__ off,
                    const unsigned short* __restrict__ P, const unsigned short* __restrict__ shP,
                    float* __restrict__ out) {
  const int n = blockIdx.x;
  const int tid = threadIdx.x;
  int rows[4];
  #pragma unroll
  for (int k = 0; k < TOPK; ++k) {
    const int ep = tokEP[n * TOPK + k];
    rows[k] = off[ep >> 16] + (ep & 0xffff);
  }
  const int cc = tid * 8;
  float4 o0 = {0, 0, 0, 0}, o1 = {0, 0, 0, 0};
  #pragma unroll
  for (int k = 0; k < TOPK; ++k) {
    const u16x8 v = *reinterpret_cast<const u16x8*>(P + (size_t)rows[k] * DIM + cc);
    o0.x += b2f(v[0]); o0.y += b2f(v[1]); o0.z += b2f(v[2]); o0.w += b2f(v[3]);
    o1.x += b2f(v[4]); o1.y += b2f(v[5]); o1.z += b2f(v[6]); o1.w += b2f(v[7]);
  }
  #pragma unroll
  for (int j = 0; j < 4; ++j) {
    const u16x8 v = *reinterpret_cast<const u16x8*>(shP + ((size_t)j * N_TOK + n) * DIM + cc);
    o0.x += b2f(v[0]); o0.y += b2f(v[1]); o0.z += b2f(v[2]); o0.w += b2f(v[3]);
    o1.x += b2f(v[4]); o1.y += b2f(v[5]); o1.z += b2f(v[6]); o1.w += b2f(v[7]);
  }
  float* po = out + (size_t)n * DIM + cc;
  *reinterpret_cast<float4*>(po) = o0;
  *reinterpret_cast<float4*>(po + 4) = o1;
}

extern "C" void kernel_launch(void* const* d_in, const int* in_sizes, int n_in,
                              void* d_out, int out_size, void* d_ws, size_t ws_size,
                              hipStream_t stream) {
  const float* x   = (const float*)d_in[0];
  const float* rw  = (const float*)d_in[1];
  const float* rb  = (const float*)d_in[2];
  const float* wg  = (const float*)d_in[3];
  const float* wu  = (const float*)d_in[4];
  const float* wd  = (const float*)d_in[5];
  const float* swg = (const float*)d_in[6];
  const float* swu = (const float*)d_in[7];
  const float* swd = (const float*)d_in[8];
  float* out = (float*)d_out;
  char* ws = (char*)d_ws;

  int* cnt = (int*)ws;
  int* off = (int*)(ws + 256);
  int* tokEP = (int*)(ws + 4096);
  int* listTok = (int*)(ws + 64 * 1024);
  float* listW = (float*)(ws + 576 * 1024);
  unsigned short* xb   = (unsigned short*)(ws + (size_t) 2 * 1024 * 1024);  //  8 MB
  unsigned short* Hr   = (unsigned short*)(ws + (size_t)10 * 1024 * 1024);  //  8 MB
  unsigned short* Hs   = (unsigned short*)(ws + (size_t)18 * 1024 * 1024);  // 16 MB
  unsigned short* swuT = (unsigned short*)(ws + (size_t)34 * 1024 * 1024);  // 16 MB
  unsigned short* swgT = (unsigned short*)(ws + (size_t)50 * 1024 * 1024);  // 16 MB
  unsigned short* swdT = (unsigned short*)(ws + (size_t)66 * 1024 * 1024);  // 16 MB
  unsigned short* P    = (unsigned short*)(ws + (size_t)82 * 1024 * 1024);  // 32 MB
  // shP aliases swuT+swgT (32 MB) — dead after up_shared completes (stream-serial).
  unsigned short* shP  = swuT;

  hipMemsetAsync(cnt, 0, NEXP * sizeof(int), stream);
  cvt_x_kernel<<<(N_TOK * DIM) / (256 * 8), 256, 0, stream>>>(x, xb);
  router_kernel<<<N_TOK / 8, 256, 0, stream>>>(x, rw, rb, cnt, listTok, listW, tokEP);
  scan_kernel<<<1, 64, 0, stream>>>(cnt, off);
  tr_shared_kernel<<<dim3(32, 32, 6), 256, 0, stream>>>(swu, swg, swd, swuT, swgT, swdT);

  up_shared<<<dim3(HSH / 64, NSH, N_TOK / 128), 256, 0, stream>>>(xb, swuT, swgT, Hs);
  up_routed<<<dim3(FDIM / 64, NEXP, 8), 256, 0, stream>>>(xb, wu, wg, cnt, off, listTok, listW, Hr);
  down_shared<<<dim3(DIM / 128, 4, N_TOK / 128), 256, 0, stream>>>(Hs, swdT, shP);
  down_routed<<<dim3(DIM / 128, NEXP, 8), 256, 0, stream>>>(Hr, wd, cnt, off, P);
  combine_kernel<<<N_TOK, 256, 0, stream>>>(tokEP, off, P, shP, out);
}

// Round 16
// 575.030 us; speedup vs baseline: 1.7080x; 1.0634x over previous
//
#include <hip/hip_runtime.h>
#include <hip/hip_bf16.h>

typedef __bf16 bf16x8 __attribute__((ext_vector_type(8)));
typedef float f32x4 __attribute__((ext_vector_type(4)));
typedef unsigned short u16x4 __attribute__((ext_vector_type(4)));
typedef unsigned short u16x8 __attribute__((ext_vector_type(8)));

#define DEVI __device__ __forceinline__

constexpr int N_TOK = 2048;
constexpr int DIM   = 2048;
constexpr int NEXP  = 64;
constexpr int FDIM  = 512;
constexpr int TOPK  = 4;
constexpr int NSH   = 2;
constexpr int HSH   = 2048;

DEVI unsigned short f2b(float f) {
  union { float fv; unsigned u; } v; v.fv = f;
  unsigned r = v.u + 0x7fffu + ((v.u >> 16) & 1u);
  return (unsigned short)(r >> 16);
}
DEVI float b2f(unsigned short h) {
  union { unsigned u; float f; } v; v.u = ((unsigned)h) << 16;
  return v.f;
}
DEVI void gll16(const void* g, void* l) {
  __builtin_amdgcn_global_load_lds((const __attribute__((address_space(1))) unsigned*)g,
                                   (__attribute__((address_space(3))) unsigned*)l, 16, 0, 0);
}
DEVI unsigned cvtpk(float lo, float hi) {
  unsigned r;
  asm("v_cvt_pk_bf16_f32 %0, %1, %2" : "=v"(r) : "v"(lo), "v"(hi));
  return r;
}
// bf16x8 B-fragment from f32 LDS tile, 8 consecutive k rows at one column; row stride str floats.
DEVI bf16x8 fragB(const float* base, int str) {
  union { unsigned u[4]; bf16x8 v; } r;
  #pragma unroll
  for (int p = 0; p < 4; ++p) r.u[p] = cvtpk(base[(2 * p) * str], base[(2 * p + 1) * str]);
  return r.v;
}

// ---------------- x -> bf16 ----------------
__global__ void cvt_x_kernel(const float* __restrict__ x, unsigned short* __restrict__ xb) {
  const size_t i = ((size_t)blockIdx.x * 256 + threadIdx.x) * 8;
  const float4 a = *reinterpret_cast<const float4*>(x + i);
  const float4 b = *reinterpret_cast<const float4*>(x + i + 4);
  u16x8 o;
  o[0] = f2b(a.x); o[1] = f2b(a.y); o[2] = f2b(a.z); o[3] = f2b(a.w);
  o[4] = f2b(b.x); o[5] = f2b(b.y); o[6] = f2b(b.z); o[7] = f2b(b.w);
  *reinterpret_cast<u16x8*>(xb + i) = o;
}

// ---------------- shared weights: transpose + bf16 ----------------
__global__ __launch_bounds__(256)
void tr_shared_kernel(const float* __restrict__ swu, const float* __restrict__ swg,
                      const float* __restrict__ swd, unsigned short* __restrict__ swuT,
                      unsigned short* __restrict__ swgT, unsigned short* __restrict__ swdT) {
  __shared__ float Lf[64][68];
  const int tid = threadIdx.x;
  const int r0 = blockIdx.x * 64, c0 = blockIdx.y * 64;
  const int z = blockIdx.z, mat = z >> 1;
  const size_t soff = (size_t)(z & 1) * DIM * HSH;
  const float* in = (mat == 0 ? swu : mat == 1 ? swg : swd) + soff;
  unsigned short* ot = (mat == 0 ? swuT : mat == 1 ? swgT : swdT) + soff;
  #pragma unroll
  for (int j = 0; j < 4; ++j) {
    const int idx = j * 1024 + tid * 4;
    const int row = idx >> 6, col = idx & 63;
    const float4 v = *reinterpret_cast<const float4*>(in + (size_t)(r0 + row) * 2048 + c0 + col);
    *reinterpret_cast<float4*>(&Lf[row][col]) = v;
  }
  __syncthreads();
  #pragma unroll
  for (int j = 0; j < 4; ++j) {
    const int idx = j * 1024 + tid * 4;
    const int orow = idx >> 6, ocol = idx & 63;
    u16x4 o;
    o[0] = f2b(Lf[ocol][orow]);     o[1] = f2b(Lf[ocol + 1][orow]);
    o[2] = f2b(Lf[ocol + 2][orow]); o[3] = f2b(Lf[ocol + 3][orow]);
    *reinterpret_cast<u16x4*>(ot + (size_t)(c0 + orow) * 2048 + r0 + ocol) = o;
  }
}

// ---------------- Router ----------------
__global__ __launch_bounds__(256)
void router_kernel(const float* __restrict__ x, const float* __restrict__ rw,
                   const float* __restrict__ rb, int* __restrict__ cnt,
                   int* __restrict__ listTok, float* __restrict__ listW,
                   int* __restrict__ tokEP) {
  __shared__ float Lx[8][128];
  const int tid = threadIdx.x;
  const int lane = tid & 63;
  const int wave = tid >> 6;
  const int tokBase = blockIdx.x * 8;

  float acc0 = 0.f, acc1 = 0.f;
  for (int dc = 0; dc < DIM; dc += 128) {
    __syncthreads();
    {
      const int idx = tid * 4;
      const int row = idx >> 7, col = idx & 127;
      *reinterpret_cast<float4*>(&Lx[row][col]) =
          *reinterpret_cast<const float4*>(x + (size_t)(tokBase + row) * DIM + dc + col);
    }
    __syncthreads();
    #pragma unroll 16
    for (int dd = 0; dd < 128; ++dd) {
      const float r = rw[(size_t)(dc + dd) * NEXP + lane];
      acc0 = fmaf(Lx[wave * 2 + 0][dd], r, acc0);
      acc1 = fmaf(Lx[wave * 2 + 1][dd], r, acc1);
    }
  }

  const float bias = rb[lane];
  #pragma unroll
  for (int t = 0; t < 2; ++t) {
    const float v = (t == 0) ? acc0 : acc1;
    const int token = tokBase + wave * 2 + t;
    float m = v;
    #pragma unroll
    for (int o = 32; o > 0; o >>= 1) m = fmaxf(m, __shfl_xor(m, o));
    const float p = expf(v - m);
    float ss = p;
    #pragma unroll
    for (int o = 32; o > 0; o >>= 1) ss += __shfl_xor(ss, o);
    const float score = p / ss;
    float cur = v + bias;
    float wk[TOPK]; int ik[TOPK]; float wsum = 0.f;
    #pragma unroll
    for (int k = 0; k < TOPK; ++k) {
      float tm = cur;
      #pragma unroll
      for (int o = 32; o > 0; o >>= 1) tm = fmaxf(tm, __shfl_xor(tm, o));
      const unsigned long long msk = __ballot(cur == tm);
      const int sel = (int)__builtin_ctzll(msk);
      const float w = __shfl(score, sel);
      wk[k] = w; ik[k] = sel; wsum += w;
      if (lane == sel) cur = -3.4e38f;
    }
    if (lane < TOPK) {
      const int e = ik[lane];
      const float w = wk[lane] / wsum;
      const int slot = atomicAdd(&cnt[e], 1);
      listTok[(size_t)e * N_TOK + slot] = token;
      listW[(size_t)e * N_TOK + slot] = w;
      tokEP[token * TOPK + lane] = (e << 16) | slot;
    }
  }
}

__global__ void scan_kernel(const int* __restrict__ cnt, int* __restrict__ off) {
  if (threadIdx.x == 0) {
    int s = 0;
    for (int e = 0; e < NEXP; ++e) { off[e] = s; s += cnt[e]; }
  }
}

// ---------------- Shared up (fused U+G): BM=128, BN=64(x2 mats), BK=64, single-buf m97 ----------------
__global__ __launch_bounds__(256, 4)
void up_shared(const unsigned short* __restrict__ xb,
               const unsigned short* __restrict__ WuT, const unsigned short* __restrict__ WgT,
               unsigned short* __restrict__ H) {
  constexpr int NT = DIM / 64;  // 32
  const int tid = threadIdx.x;
  const int f0 = blockIdx.x * 64;
  const int s  = blockIdx.y;
  const int m0 = blockIdx.z * 128;

  __shared__ __align__(16) unsigned short Al[8][128][8];   // 16 KB
  __shared__ __align__(16) unsigned short BuL[8][64][8];   //  8 KB
  __shared__ __align__(16) unsigned short BgL[8][64][8];   //  8 KB

  const int wid = tid >> 6, l = tid & 63;
  const int lc = l & 15, hi = l >> 4;

  const unsigned short* pa0 = xb + (size_t)(m0 + l) * DIM;
  const unsigned short* pa1 = xb + (size_t)(m0 + 64 + l) * DIM;
  const unsigned short* pbu = WuT + (size_t)s * HSH * DIM + (size_t)(f0 + l) * DIM;
  const unsigned short* pbg = WgT + (size_t)s * HSH * DIM + (size_t)(f0 + l) * DIM;

  f32x4 aU[2][4], aG[2][4];
  #pragma unroll
  for (int i = 0; i < 2; ++i)
    #pragma unroll
    for (int j = 0; j < 4; ++j) { aU[i][j] = f32x4{0,0,0,0}; aG[i][j] = f32x4{0,0,0,0}; }

  for (int g = 0; g < NT; ++g) {
    const int d0 = g * 64;
    #pragma unroll
    for (int i = 0; i < 4; ++i) {           // A: 16 wave-loads total
      const int idx = wid * 4 + i;
      const int p = idx >> 1, hf = idx & 1;
      gll16((hf ? pa1 : pa0) + d0 + p * 8, &Al[p][hf * 64][0]);
    }
    #pragma unroll
    for (int i = 0; i < 2; ++i) {           // B: 8+8 wave-loads total
      const int p = wid * 2 + i;
      gll16(pbu + d0 + p * 8, &BuL[p][0][0]);
      gll16(pbg + d0 + p * 8, &BgL[p][0][0]);
    }
    __syncthreads();
    #pragma unroll
    for (int ks = 0; ks < 2; ++ks) {
      bf16x8 af[2], bu[4], bg[4];
      #pragma unroll
      for (int mi = 0; mi < 2; ++mi)
        af[mi] = *reinterpret_cast<const bf16x8*>(&Al[ks * 4 + hi][wid * 32 + mi * 16 + lc][0]);
      #pragma unroll
      for (int ni = 0; ni < 4; ++ni) {
        bu[ni] = *reinterpret_cast<const bf16x8*>(&BuL[ks * 4 + hi][ni * 16 + lc][0]);
        bg[ni] = *reinterpret_cast<const bf16x8*>(&BgL[ks * 4 + hi][ni * 16 + lc][0]);
      }
      #pragma unroll
      for (int mi = 0; mi < 2; ++mi)
        #pragma unroll
        for (int ni = 0; ni < 4; ++ni) {
          aU[mi][ni] = __builtin_amdgcn_mfma_f32_16x16x32_bf16(af[mi], bu[ni], aU[mi][ni], 0, 0, 0);
          aG[mi][ni] = __builtin_amdgcn_mfma_f32_16x16x32_bf16(af[mi], bg[ni], aG[mi][ni], 0, 0, 0);
        }
    }
    __syncthreads();
  }

  #pragma unroll
  for (int mi = 0; mi < 2; ++mi)
    #pragma unroll
    for (int ni = 0; ni < 4; ++ni)
      #pragma unroll
      for (int r2 = 0; r2 < 4; ++r2) {
        const int row = wid * 32 + mi * 16 + hi * 4 + r2;
        const int col = f0 + ni * 16 + lc;
        const float g = aG[mi][ni][r2], u = aU[mi][ni][r2];
        H[((size_t)s * N_TOK + m0 + row) * HSH + col] = f2b((g / (1.f + __expf(-g))) * u);
      }
}

// ---------------- Shared down: BM=128, BN=128, K-split x4 -> bf16 partials ----------------
__global__ __launch_bounds__(256, 4)
void down_shared(const unsigned short* __restrict__ Hs, const unsigned short* __restrict__ swdT,
                 unsigned short* __restrict__ shP) {
  constexpr int NT = 16;  // K-chunk 1024
  const int tid = threadIdx.x;
  const int x0 = blockIdx.x * 128;
  const int kc = blockIdx.y;            // 0..3
  const int m0 = blockIdx.z * 128;
  const int seg = kc >> 1;
  const int kb = (kc & 1) * 1024;

  __shared__ __align__(16) unsigned short Al[8][128][8];   // 16 KB
  __shared__ __align__(16) unsigned short Bl[8][128][8];   // 16 KB

  const int wid = tid >> 6, l = tid & 63;
  const int lc = l & 15, hi = l >> 4;

  const unsigned short* pa0 = Hs + ((size_t)seg * N_TOK + m0 + l) * HSH + kb;
  const unsigned short* pa1 = Hs + ((size_t)seg * N_TOK + m0 + 64 + l) * HSH + kb;
  const unsigned short* pb0 = swdT + (size_t)seg * HSH * DIM + (size_t)(x0 + l) * HSH + kb;
  const unsigned short* pb1 = swdT + (size_t)seg * HSH * DIM + (size_t)(x0 + 64 + l) * HSH + kb;

  f32x4 acc[2][8];
  #pragma unroll
  for (int i = 0; i < 2; ++i)
    #pragma unroll
    for (int j = 0; j < 8; ++j) acc[i][j] = f32x4{0,0,0,0};

  for (int g = 0; g < NT; ++g) {
    const int d0 = g * 64;
    #pragma unroll
    for (int i = 0; i < 4; ++i) {
      const int idx = wid * 4 + i;
      const int p = idx >> 1, hf = idx & 1;
      gll16((hf ? pa1 : pa0) + d0 + p * 8, &Al[p][hf * 64][0]);
      gll16((hf ? pb1 : pb0) + d0 + p * 8, &Bl[p][hf * 64][0]);
    }
    __syncthreads();
    #pragma unroll
    for (int ks = 0; ks < 2; ++ks) {
      bf16x8 af[2], bq[8];
      #pragma unroll
      for (int mi = 0; mi < 2; ++mi)
        af[mi] = *reinterpret_cast<const bf16x8*>(&Al[ks * 4 + hi][wid * 32 + mi * 16 + lc][0]);
      #pragma unroll
      for (int ni = 0; ni < 8; ++ni)
        bq[ni] = *reinterpret_cast<const bf16x8*>(&Bl[ks * 4 + hi][ni * 16 + lc][0]);
      #pragma unroll
      for (int mi = 0; mi < 2; ++mi)
        #pragma unroll
        for (int ni = 0; ni < 8; ++ni)
          acc[mi][ni] = __builtin_amdgcn_mfma_f32_16x16x32_bf16(af[mi], bq[ni], acc[mi][ni], 0, 0, 0);
    }
    __syncthreads();
  }

  unsigned short* pout = shP + (size_t)kc * N_TOK * DIM;
  #pragma unroll
  for (int mi = 0; mi < 2; ++mi)
    #pragma unroll
    for (int ni = 0; ni < 8; ++ni)
      #pragma unroll
      for (int r2 = 0; r2 < 4; ++r2) {
        const int row = wid * 32 + mi * 16 + hi * 4 + r2;
        const int col = x0 + ni * 16 + lc;
        pout[(size_t)(m0 + row) * DIM + col] = f2b(acc[mi][ni][r2]);
      }
}

// ---------------- Routed up (fused U+G): BM=256, BN=64(x2), f32 B via gll16+fragB ----------------
__global__ __launch_bounds__(256, 2)
void up_routed(const unsigned short* __restrict__ xb,
               const float* __restrict__ Wu, const float* __restrict__ Wg,
               const int* __restrict__ cnt, const int* __restrict__ off,
               const int* __restrict__ listTok, const float* __restrict__ listW,
               unsigned short* __restrict__ H) {
  constexpr int NT = DIM / 64;  // 32
  const int tid = threadIdx.x;
  const int f0 = blockIdx.x * 64;
  const int e  = blockIdx.y;
  const int m0 = blockIdx.z * 256;
  const int c = cnt[e];
  if (m0 >= c) return;
  const int rc = min(256, c - m0);
  const int rowbase = off[e] + m0;

  __shared__ __align__(16) unsigned short Al[8][256][8];   // 32 KB
  __shared__ __align__(16) float Bfu[64][64];              // 16 KB
  __shared__ __align__(16) float Bfg[64][64];              // 16 KB
  __shared__ float wSs[256];

  wSs[tid] = (m0 + tid < c) ? listW[(size_t)e * N_TOK + m0 + tid] : 0.f;

  const int wid = tid >> 6, l = tid & 63;
  const int lc = l & 15, hi = l >> 4;

  const unsigned short* pa[4];
  #pragma unroll
  for (int j = 0; j < 4; ++j) {
    const int tok = listTok[(size_t)e * N_TOK + min(m0 + j * 64 + l, c - 1)];
    pa[j] = xb + (size_t)tok * DIM;
  }
  const float* pwu = Wu + (size_t)e * DIM * FDIM + (size_t)(l >> 4) * FDIM + f0 + (l & 15) * 4;
  const float* pwg = Wg + (size_t)e * DIM * FDIM + (size_t)(l >> 4) * FDIM + f0 + (l & 15) * 4;

  f32x4 aU[4][4], aG[4][4];
  #pragma unroll
  for (int i = 0; i < 4; ++i)
    #pragma unroll
    for (int j = 0; j < 4; ++j) { aU[i][j] = f32x4{0,0,0,0}; aG[i][j] = f32x4{0,0,0,0}; }

  for (int g = 0; g < NT; ++g) {
    const int d0 = g * 64;
    #pragma unroll
    for (int i = 0; i < 8; ++i) {           // A: 32 wave-loads total
      const int idx = wid * 8 + i;
      const int p = idx >> 2, j = idx & 3;
      gll16(pa[j] + d0 + p * 8, &Al[p][j * 64][0]);
    }
    #pragma unroll
    for (int i = 0; i < 4; ++i) {           // B: 16+16 wave-loads (4 k-rows each)
      const int krow = (wid * 4 + i) * 4;
      gll16(pwu + (size_t)(d0 + krow) * FDIM, &Bfu[krow][0]);
      gll16(pwg + (size_t)(d0 + krow) * FDIM, &Bfg[krow][0]);
    }
    __syncthreads();
    #pragma unroll
    for (int ks = 0; ks < 2; ++ks) {
      bf16x8 af[4];
      #pragma unroll
      for (int mi = 0; mi < 4; ++mi)
        af[mi] = *reinterpret_cast<const bf16x8*>(&Al[ks * 4 + hi][wid * 64 + mi * 16 + lc][0]);
      #pragma unroll
      for (int ni = 0; ni < 4; ++ni) {
        const bf16x8 bu = fragB(&Bfu[ks * 32 + hi * 8][ni * 16 + lc], 64);
        const bf16x8 bg = fragB(&Bfg[ks * 32 + hi * 8][ni * 16 + lc], 64);
        #pragma unroll
        for (int mi = 0; mi < 4; ++mi) {
          aU[mi][ni] = __builtin_amdgcn_mfma_f32_16x16x32_bf16(af[mi], bu, aU[mi][ni], 0, 0, 0);
          aG[mi][ni] = __builtin_amdgcn_mfma_f32_16x16x32_bf16(af[mi], bg, aG[mi][ni], 0, 0, 0);
        }
      }
    }
    __syncthreads();
  }

  #pragma unroll
  for (int mi = 0; mi < 4; ++mi)
    #pragma unroll
    for (int ni = 0; ni < 4; ++ni)
      #pragma unroll
      for (int r2 = 0; r2 < 4; ++r2) {
        const int row = wid * 64 + mi * 16 + hi * 4 + r2;
        if (row < rc) {
          const int col = f0 + ni * 16 + lc;
          const float g = aG[mi][ni][r2], u = aU[mi][ni][r2];
          const float h = (g / (1.f + __expf(-g))) * u * wSs[row];
          H[(size_t)(rowbase + row) * FDIM + col] = f2b(h);
        }
      }
}

// ---------------- Routed down: BM=256, BN=128, K=512, f32 B via gll16+fragB -> P ----------------
__global__ __launch_bounds__(256, 2)
void down_routed(const unsigned short* __restrict__ Hr, const float* __restrict__ wd,
                 const int* __restrict__ cnt, const int* __restrict__ off,
                 unsigned short* __restrict__ P) {
  constexpr int NT = FDIM / 64;  // 8
  const int tid = threadIdx.x;
  const int x0 = blockIdx.x * 128;
  const int e  = blockIdx.y;
  const int m0 = blockIdx.z * 256;
  const int c = cnt[e];
  if (m0 >= c) return;
  const int rc = min(256, c - m0);
  const int rowbase = off[e] + m0;

  __shared__ __align__(16) unsigned short Al[8][256][8];   // 32 KB
  __shared__ __align__(16) float Bf[64][128];              // 32 KB

  const int wid = tid >> 6, l = tid & 63;
  const int lc = l & 15, hi = l >> 4;

  const unsigned short* pa[4];
  #pragma unroll
  for (int j = 0; j < 4; ++j)
    pa[j] = Hr + (size_t)(rowbase + min(j * 64 + l, c - m0 - 1)) * FDIM;

  const float* pwd = wd + (size_t)e * FDIM * DIM + (size_t)(l >> 5) * DIM + x0 + (l & 31) * 4;

  f32x4 acc[4][8];
  #pragma unroll
  for (int i = 0; i < 4; ++i)
    #pragma unroll
    for (int j = 0; j < 8; ++j) acc[i][j] = f32x4{0,0,0,0};

  for (int g = 0; g < NT; ++g) {
    const int d0 = g * 64;
    #pragma unroll
    for (int i = 0; i < 8; ++i) {           // A: 32 wave-loads
      const int idx = wid * 8 + i;
      const int p = idx >> 2, j = idx & 3;
      gll16(pa[j] + d0 + p * 8, &Al[p][j * 64][0]);
    }
    #pragma unroll
    for (int i = 0; i < 8; ++i) {           // B: 32 wave-loads (2 k-rows each)
      const int krow = (wid * 8 + i) * 2;
      gll16(pwd + (size_t)(d0 + krow) * DIM, &Bf[krow][0]);
    }
    __syncthreads();
    #pragma unroll
    for (int ks = 0; ks < 2; ++ks) {
      bf16x8 af[4];
      #pragma unroll
      for (int mi = 0; mi < 4; ++mi)
        af[mi] = *reinterpret_cast<const bf16x8*>(&Al[ks * 4 + hi][wid * 64 + mi * 16 + lc][0]);
      #pragma unroll
      for (int ni = 0; ni < 8; ++ni) {
        const bf16x8 bq = fragB(&Bf[ks * 32 + hi * 8][ni * 16 + lc], 128);
        #pragma unroll
        for (int mi = 0; mi < 4; ++mi)
          acc[mi][ni] = __builtin_amdgcn_mfma_f32_16x16x32_bf16(af[mi], bq, acc[mi][ni], 0, 0, 0);
      }
    }
    __syncthreads();
  }

  #pragma unroll
  for (int mi = 0; mi < 4; ++mi)
    #pragma unroll
    for (int ni = 0; ni < 8; ++ni)
      #pragma unroll
      for (int r2 = 0; r2 < 4; ++r2) {
        const int row = wid * 64 + mi * 16 + hi * 4 + r2;
        if (row < rc) {
          const int col = x0 + ni * 16 + lc;
          P[(size_t)(rowbase + row) * DIM + col] = f2b(acc[mi][ni][r2]);
        }
      }
}

// ---------------- Combine: out[n] = sum_k routedP[slot(n,k)] + sum_j shP[j][n] ----------------
__global__ __launch_bounds__(256)
void combine_kernel(const int* __restrict__ tokEP, const int* __restrict__ off,
                    const unsigned short* __restrict__ P, const unsigned short* __restrict__ shP,
                    float* __restrict__ out) {
  const int n = blockIdx.x;
  const int tid = threadIdx.x;
  int rows[4];
  #pragma unroll
  for (int k = 0; k < TOPK; ++k) {
    const int ep = tokEP[n * TOPK + k];
    rows[k] = off[ep >> 16] + (ep & 0xffff);
  }
  const int cc = tid * 8;
  float4 o0 = {0, 0, 0, 0}, o1 = {0, 0, 0, 0};
  #pragma unroll
  for (int k = 0; k < TOPK; ++k) {
    const u16x8 v = *reinterpret_cast<const u16x8*>(P + (size_t)rows[k] * DIM + cc);
    o0.x += b2f(v[0]); o0.y += b2f(v[1]); o0.z += b2f(v[2]); o0.w += b2f(v[3]);
    o1.x += b2f(v[4]); o1.y += b2f(v[5]); o1.z += b2f(v[6]); o1.w += b2f(v[7]);
  }
  #pragma unroll
  for (int j = 0; j < 4; ++j) {
    const u16x8 v = *reinterpret_cast<const u16x8*>(shP + ((size_t)j * N_TOK + n) * DIM + cc);
    o0.x += b2f(v[0]); o0.y += b2f(v[1]); o0.z += b2f(v[2]); o0.w += b2f(v[3]);
    o1.x += b2f(v[4]); o1.y += b2f(v[5]); o1.z += b2f(v[6]); o1.w += b2f(v[7]);
  }
  float* po = out + (size_t)n * DIM + cc;
  *reinterpret_cast<float4*>(po) = o0;
  *reinterpret_cast<float4*>(po + 4) = o1;
}

extern "C" void kernel_launch(void* const* d_in, const int* in_sizes, int n_in,
                              void* d_out, int out_size, void* d_ws, size_t ws_size,
                              hipStream_t stream) {
  const float* x   = (const float*)d_in[0];
  const float* rw  = (const float*)d_in[1];
  const float* rb  = (const float*)d_in[2];
  const float* wg  = (const float*)d_in[3];
  const float* wu  = (const float*)d_in[4];
  const float* wd  = (const float*)d_in[5];
  const float* swg = (const float*)d_in[6];
  const float* swu = (const float*)d_in[7];
  const float* swd = (const float*)d_in[8];
  float* out = (float*)d_out;
  char* ws = (char*)d_ws;

  int* cnt = (int*)ws;
  int* off = (int*)(ws + 256);
  int* tokEP = (int*)(ws + 4096);
  int* listTok = (int*)(ws + 64 * 1024);
  float* listW = (float*)(ws + 576 * 1024);
  unsigned short* xb   = (unsigned short*)(ws + (size_t) 2 * 1024 * 1024);  //  8 MB
  unsigned short* Hr   = (unsigned short*)(ws + (size_t)10 * 1024 * 1024);  //  8 MB
  unsigned short* Hs   = (unsigned short*)(ws + (size_t)18 * 1024 * 1024);  // 16 MB
  unsigned short* swuT = (unsigned short*)(ws + (size_t)34 * 1024 * 1024);  // 16 MB
  unsigned short* swgT = (unsigned short*)(ws + (size_t)50 * 1024 * 1024);  // 16 MB
  unsigned short* swdT = (unsigned short*)(ws + (size_t)66 * 1024 * 1024);  // 16 MB
  unsigned short* P    = (unsigned short*)(ws + (size_t)82 * 1024 * 1024);  // 32 MB
  // shP aliases swuT+swgT (32 MB) — dead after up_shared completes (stream-serial).
  unsigned short* shP  = swuT;

  hipMemsetAsync(cnt, 0, NEXP * sizeof(int), stream);
  cvt_x_kernel<<<(N_TOK * DIM) / (256 * 8), 256, 0, stream>>>(x, xb);
  router_kernel<<<N_TOK / 8, 256, 0, stream>>>(x, rw, rb, cnt, listTok, listW, tokEP);
  scan_kernel<<<1, 64, 0, stream>>>(cnt, off);
  tr_shared_kernel<<<dim3(32, 32, 6), 256, 0, stream>>>(swu, swg, swd, swuT, swgT, swdT);

  // shared up must finish before shP overwrites swuT/swgT (stream-serial)
  up_shared<<<dim3(HSH / 64, NSH, N_TOK / 128), 256, 0, stream>>>(xb, swuT, swgT, Hs);
  up_routed<<<dim3(FDIM / 64, NEXP, 8), 256, 0, stream>>>(xb, wu, wg, cnt, off, listTok, listW, Hr);
  down_shared<<<dim3(DIM / 128, 4, N_TOK / 128), 256, 0, stream>>>(Hs, swdT, shP);
  down_routed<<<dim3(DIM / 128, NEXP, 8), 256, 0, stream>>>(Hr, wd, cnt, off, P);
  combine_kernel<<<N_TOK, 256, 0, stream>>>(tokEP, off, P, shP, out);
}